// Round 18
// baseline (1427.650 us; speedup 1.0000x reference)
//
#include <hip/hip_runtime.h>
#include <math.h>

#define DM 512

typedef __attribute__((ext_vector_type(8))) short short8v;
typedef __attribute__((ext_vector_type(4))) float floatx4;
typedef _Float16 half8v __attribute__((ext_vector_type(8)));
typedef _Float16 half2v __attribute__((ext_vector_type(2)));

__device__ inline unsigned short f2b(float x){
  unsigned u = __builtin_bit_cast(unsigned, x);
  u += 0x7fffu + ((u >> 16) & 1u);
  return (unsigned short)(u >> 16);
}
__device__ inline float b2f(unsigned short h){
  unsigned u = ((unsigned)h) << 16;
  return __builtin_bit_cast(float, u);
}

__device__ inline float wave_sum(float v){
  #pragma unroll
  for (int off=32; off; off>>=1) v += __shfl_xor(v, off);
  return v;
}
__device__ inline float wave_max(float v){
  #pragma unroll
  for (int off=32; off; off>>=1) v = fmaxf(v, __shfl_xor(v, off));
  return v;
}

__device__ inline void gload16(const unsigned short* g, unsigned short* l){
  __builtin_amdgcn_global_load_lds(
      (const __attribute__((address_space(1))) unsigned int*)g,
      (__attribute__((address_space(3))) unsigned int*)l, 16, 0, 0);
}

// ---------------------------------------------------------------------------
// bf16 MFMA GEMM — T4 counted-vmcnt 3-buffer pipeline (depth 2), T2 swizzle.
// JF=4: 128x128 tile. JF=2: 128x64 tile (N<=512).
// omode bit0: fp32 C (bit3: accumulate). bit1: bf16 Cb. bit2: bf16 transposed
// per-batch-480. bit4: segmented-N. bit5 (32): fast epilogue emits FP16
// instead of bf16 (stage-5 Q/K/V, consumed only by slide kernels via fdot2).
// XCD-aware bijective swizzle (m204). Requires K % 32 == 0.
// ---------------------------------------------------------------------------
template<int JF>
__global__ __launch_bounds__(256) void gemm_mfma(
    const unsigned short* __restrict__ A, const unsigned short* __restrict__ Bt,
    const float* __restrict__ bias, float* __restrict__ C,
    unsigned short* __restrict__ Cb,
    int M, int N, int K, int lda, int ldb, int ldc,
    long long aB, long long bB, long long cB,
    float preS, float postS, int act, int omode)
{
  constexpr int ASZ = 4096;           // shorts per A buffer (128 x 32)
  constexpr int BSZ = JF * 1024;      // shorts per B buffer (JF*32 x 32)
  __shared__ alignas(16) unsigned short SM[3 * (ASZ + BSZ)];
  const int z = blockIdx.z;
  A += (long long)z * aB;
  Bt += (long long)z * bB;
  const int tid = threadIdx.x;
  const int w = tid >> 6, l = tid & 63;

  // XCD swizzle (bijective, m204); skip tiny grids
  int nwg = gridDim.x * gridDim.y;
  int orig = blockIdx.y * gridDim.x + blockIdx.x;
  int wgid = orig;
  if (nwg >= 16) {
    int qq = nwg >> 3, r = nwg & 7;
    int xcd = orig & 7, pos = orig >> 3;
    wgid = (xcd < r ? xcd * (qq + 1) : r * (qq + 1) + (xcd - r) * qq) + pos;
  }
  const int bx = wgid % gridDim.x, by = wgid / gridDim.x;
  const int m0 = by * 128, n0 = bx * (JF * 32);
  const int wm = (w >> 1) * 64, wn = (w & 1) * (JF * 16);
  const int srow = tid >> 2;            // 0..63 (local row this lane stages)
  const int scol = ((tid & 3) ^ ((srow >> 1) & 3)) * 8;  // T2 pre-swizzle

  floatx4 acc[4][JF];
  #pragma unroll
  for (int i = 0; i < 4; i++)
    #pragma unroll
    for (int j = 0; j < JF; j++) acc[i][j] = (floatx4)0.f;

  auto AsP = [&](int h) { return SM + h * ASZ; };
  auto BsP = [&](int h) { return SM + 3 * ASZ + h * BSZ; };

  auto stage = [&](int h, int kc) {
    gload16(A  + (long long)(m0 + srow)      * lda + kc + scol, AsP(h) + w * 512);
    gload16(A  + (long long)(m0 + 64 + srow) * lda + kc + scol, AsP(h) + 2048 + w * 512);
    gload16(Bt + (long long)(n0 + srow)      * ldb + kc + scol, BsP(h) + w * 512);
    if (JF == 4)
      gload16(Bt + (long long)(n0 + 64 + srow) * ldb + kc + scol, BsP(h) + 2048 + w * 512);
  };
  auto compute = [&](int h) {
    short8v a[4], b[JF];
    #pragma unroll
    for (int i = 0; i < 4; i++) {
      int rowA = wm + i * 16 + (l & 15);
      a[i] = *(const short8v*)&AsP(h)[rowA * 32 + (((l >> 4) ^ ((rowA >> 1) & 3)) * 8)];
    }
    #pragma unroll
    for (int j = 0; j < JF; j++) {
      int rowB = wn + j * 16 + (l & 15);
      b[j] = *(const short8v*)&BsP(h)[rowB * 32 + (((l >> 4) ^ ((rowB >> 1) & 3)) * 8)];
    }
    #pragma unroll
    for (int i = 0; i < 4; i++)
      #pragma unroll
      for (int j = 0; j < JF; j++)
        acc[i][j] = __builtin_amdgcn_mfma_f32_16x16x32_bf16(a[i], b[j], acc[i][j], 0, 0, 0);
  };
  auto wait_counted = [&]() {
    if (JF == 4) asm volatile("s_waitcnt vmcnt(4)" ::: "memory");
    else         asm volatile("s_waitcnt vmcnt(3)" ::: "memory");
  };

  // ---- T4 counted-vmcnt K-loop (half-tile = 32; K % 32 == 0) ----
  const int nsteps = K >> 5;
  stage(0, 0);
  if (nsteps > 1) {
    stage(1, 32);
    wait_counted();                     // tile 0 (older NL loads) resident
  } else {
    asm volatile("s_waitcnt vmcnt(0)" ::: "memory");
  }
  __builtin_amdgcn_s_barrier();
  __builtin_amdgcn_sched_barrier(0);
  for (int s = 0; s < nsteps; s++) {
    if (s + 2 < nsteps) stage((s + 2) % 3, (s + 2) << 5);
    compute(s % 3);
    if (s + 1 < nsteps) {
      if (s + 2 < nsteps) wait_counted();                       // tile s+1 done
      else asm volatile("s_waitcnt vmcnt(0)" ::: "memory");     // tail drain
      __builtin_amdgcn_s_barrier();
      __builtin_amdgcn_sched_barrier(0);
    }
  }

  // ---- fast epilogue: bf16/fp16-only output (optionally segmented) ----
  if (((omode & 13) == 0) && (omode & 2)) {
    const bool f16out = (omode & 32) != 0;
    float* E = (float*)SM;
    constexpr int HC = JF * 16;                 // cols per half (JF4:64, JF2:32)
    constexpr int NCH = (128 * HC) / (256 * 8); // 16B chunks per thread per half
    #pragma unroll
    for (int half = 0; half < 2; half++) {
      __syncthreads();
      if ((w & 1) == half) {
        #pragma unroll
        for (int i = 0; i < 4; i++)
          #pragma unroll
          for (int r = 0; r < 4; r++) {
            int row = wm + i * 16 + (l >> 4) * 4 + r;
            #pragma unroll
            for (int j = 0; j < JF; j++) {
              int colh = j * 16 + (l & 15);
              int colg = n0 + half * HC + colh;
              float v = preS * acc[i][j][r] + (bias ? bias[colg] : 0.f);
              if (act == 1) v = fmaxf(v, 0.f);
              E[row * HC + colh] = v * postS;
            }
          }
      }
      __syncthreads();
      #pragma unroll
      for (int c = 0; c < NCH; c++) {
        int eidx = (c * 256 + tid) * 8;
        int row = eidx / HC, colh = eidx % HC;
        int grow = m0 + row;
        int gcol0 = n0 + half * HC + colh;
        if (grow < M && gcol0 < N) {
          short8v o;
          if (f16out) {
            #pragma unroll
            for (int e = 0; e < 8; e++)
              o[e] = (short)__builtin_bit_cast(unsigned short, (_Float16)E[eidx + e]);
          } else {
            #pragma unroll
            for (int e = 0; e < 8; e++) o[e] = (short)f2b(E[eidx + e]);
          }
          long long sidx = (omode & 16)
              ? (long long)(gcol0 >> 9) * cB + (long long)grow * ldc + (gcol0 & 511)
              : (long long)z * cB + (long long)grow * ldc + gcol0;
          *(short8v*)(Cb + sidx) = o;
        }
      }
    }
    return;
  }

  // ---- scalar epilogue (fp32 / accumulate / transposed / dual modes) ----
  const long long coff = (long long)z * cB;
  #pragma unroll
  for (int i = 0; i < 4; i++) {
    #pragma unroll
    for (int r = 0; r < 4; r++) {
      int row = m0 + wm + i * 16 + (l >> 4) * 4 + r;
      if (row >= M) continue;
      #pragma unroll
      for (int j = 0; j < JF; j++) {
        int col = n0 + wn + j * 16 + (l & 15);
        if (col >= N) continue;
        float v = preS * acc[i][j][r] + (bias ? bias[col] : 0.f);
        if (act == 1) v = fmaxf(v, 0.f);
        v *= postS;
        long long sidx = (omode & 16)
            ? (long long)(col >> 9) * cB + (long long)row * ldc + (col & 511)
            : coff + (long long)row * ldc + col;
        if (omode & 1) C[sidx] = (omode & 8) ? (C[sidx] + v) : v;
        if (omode & 2) Cb[sidx] = f2b(v);
        if (omode & 4) {
          int bb = row / 480, t = row - bb * 480;
          Cb[(long long)bb * (512 * 480) + (long long)col * 480 + t] = f2b(v);
        }
      }
    }
  }
}

// ---------------------------------------------------------------------------
// fp32 vector GEMM + optional bf16 dual-write. C may be nullptr.
// ---------------------------------------------------------------------------
__global__ __launch_bounds__(256) void gemm_f32(
    const float* __restrict__ A, const float* __restrict__ B,
    const float* __restrict__ bias, float* __restrict__ C,
    unsigned short* __restrict__ Cb,
    int M, int N, int K, int lda, int ldb, int ldc,
    long long aB, long long aH, long long bB, long long bH,
    long long cB, long long cH, int nh, int transB,
    float preS, float postS, int act)
{
  int z = blockIdx.z;
  int bz = z / nh, hz = z - bz * nh;
  A += (long long)bz * aB + (long long)hz * aH;
  B += (long long)bz * bB + (long long)hz * bH;
  const long long coff = (long long)bz * cB + (long long)hz * cH;

  __shared__ float As[16][65];
  __shared__ float Bs[16][65];
  const int tid = threadIdx.x;
  const int m0 = blockIdx.y * 64, n0 = blockIdx.x * 64;
  const int tx = tid & 15, ty = tid >> 4;
  float acc[4][4] = {};

  for (int k0 = 0; k0 < K; k0 += 16) {
    int am = tid >> 2, ak = (tid & 3) * 4;
    #pragma unroll
    for (int i = 0; i < 4; i++) {
      int mm = m0 + am, kk = k0 + ak + i;
      As[ak + i][am] = (mm < M && kk < K) ? A[(long long)mm * lda + kk] : 0.f;
    }
    if (!transB) {
      #pragma unroll
      for (int r = 0; r < 4; r++) {
        int kr = (tid >> 6) + r * 4;
        int kk = k0 + kr, nn = n0 + (tid & 63);
        Bs[kr][tid & 63] = (kk < K && nn < N) ? B[(long long)kk * ldb + nn] : 0.f;
      }
    } else {
      int bn = tid >> 2, bk = (tid & 3) * 4;
      #pragma unroll
      for (int i = 0; i < 4; i++) {
        int nn = n0 + bn, kk = k0 + bk + i;
        Bs[bk + i][bn] = (nn < N && kk < K) ? B[(long long)nn * ldb + kk] : 0.f;
      }
    }
    __syncthreads();
    #pragma unroll
    for (int k = 0; k < 16; k++) {
      float a4[4], b4[4];
      #pragma unroll
      for (int i = 0; i < 4; i++) { a4[i] = As[k][ty * 4 + i]; b4[i] = Bs[k][tx * 4 + i]; }
      #pragma unroll
      for (int i = 0; i < 4; i++)
        #pragma unroll
        for (int j = 0; j < 4; j++)
          acc[i][j] = fmaf(a4[i], b4[j], acc[i][j]);
    }
    __syncthreads();
  }

  #pragma unroll
  for (int i = 0; i < 4; i++) {
    int mm = m0 + ty * 4 + i;
    if (mm >= M) continue;
    #pragma unroll
    for (int j = 0; j < 4; j++) {
      int nn = n0 + tx * 4 + j;
      if (nn >= N) continue;
      float v = preS * acc[i][j] + (bias ? bias[nn] : 0.f);
      if (act == 1) v = fmaxf(v, 0.f);
      else if (act == 2) v = tanhf(v);
      v *= postS;
      if (C)  C[coff + (long long)mm * ldc + nn] = v;
      if (Cb) Cb[coff + (long long)mm * ldc + nn] = f2b(v);
    }
  }
}

// ---------------------------------------------------------------------------
// Wave-per-output dot GEMM for tiny-M head layers (bf16 in, fp32 accum).
// ---------------------------------------------------------------------------
__global__ void dot_gemm(const unsigned short* __restrict__ A,
                         const unsigned short* __restrict__ Wt,
                         const float* __restrict__ bias,
                         float* __restrict__ Cf, unsigned short* __restrict__ Cb,
                         int M, int N, int K, int act)
{
  int wid = blockIdx.x * 4 + (threadIdx.x >> 6);
  if (wid >= M * N) return;
  int m = wid / N, n = wid - m * N;
  int lane = threadIdx.x & 63;
  float s = 0.f;
  for (int k = lane * 8; k < K; k += 512) {
    short8v a = *(const short8v*)(A + (long long)m * K + k);
    short8v w = *(const short8v*)(Wt + (long long)n * K + k);
    #pragma unroll
    for (int i = 0; i < 8; i++)
      s = fmaf(b2f((unsigned short)a[i]), b2f((unsigned short)w[i]), s);
  }
  s = wave_sum(s);
  if (lane == 0) {
    s += bias[n];
    if (act == 2) s = tanhf(s);
    if (Cf) Cf[(long long)m * N + n] = s;
    if (Cb) Cb[(long long)m * N + n] = f2b(s);
  }
}

// ---------------------------------------------------------------------------
// Row softmax (fp32 in). If Sb != null, writes ONLY bf16 result.
// ---------------------------------------------------------------------------
__global__ void softmax_rows(float* __restrict__ S, unsigned short* __restrict__ Sb,
                             int R, int L, int ld)
{
  int wid = blockIdx.x * (blockDim.x >> 6) + (threadIdx.x >> 6);
  if (wid >= R) return;
  int lane = threadIdx.x & 63;
  float* p = S + (long long)wid * ld;
  float v[8];
  float m = -1e30f;
  #pragma unroll
  for (int i = 0; i < 8; i++) {
    int idx = lane + i * 64;
    v[i] = (idx < L) ? p[idx] : -1e30f;
    m = fmaxf(m, v[i]);
  }
  m = wave_max(m);
  float s = 0.f;
  #pragma unroll
  for (int i = 0; i < 8; i++) {
    v[i] = expf(v[i] - m);
    if (lane + i * 64 < L) s += v[i];
  }
  s = wave_sum(s);
  float inv = 1.f / s;
  #pragma unroll
  for (int i = 0; i < 8; i++) {
    int idx = lane + i * 64;
    if (idx < L) {
      float r = v[i] * inv;
      if (Sb) Sb[(long long)wid * ld + idx] = f2b(r);
      else    p[idx] = r;
    }
  }
}

// ---------------------------------------------------------------------------
// Fused add + LayerNorm, D=512. fp32 out (+ optional bf16 out). accum: +=.
// ---------------------------------------------------------------------------
__global__ void ln_rows(const float* __restrict__ a, const float* __restrict__ b,
                        const float* __restrict__ c, const float* __restrict__ gb,
                        float* __restrict__ out, unsigned short* __restrict__ outb,
                        int rows, int accum)
{
  int wid = blockIdx.x * (blockDim.x >> 6) + (threadIdx.x >> 6);
  if (wid >= rows) return;
  int lane = threadIdx.x & 63;
  long long base = (long long)wid * DM;
  float x[8]; float s = 0.f;
  #pragma unroll
  for (int i = 0; i < 8; i++) {
    int d = lane + i * 64;
    float v = a[base + d];
    if (b) v += b[base + d];
    if (c) v += c[base + d];
    x[i] = v; s += v;
  }
  s = wave_sum(s);
  float mean = s * (1.f / DM);
  float vs = 0.f;
  #pragma unroll
  for (int i = 0; i < 8; i++) { float d = x[i] - mean; vs += d * d; }
  vs = wave_sum(vs);
  float rstd = rsqrtf(vs * (1.f / DM) + 1e-5f);
  #pragma unroll
  for (int i = 0; i < 8; i++) {
    int d = lane + i * 64;
    float val = (x[i] - mean) * rstd * gb[d] + gb[DM + d];
    if (accum) out[base + d] += val; else out[base + d] = val;
    if (outb) outb[base + d] = f2b(val);
  }
}

// ---------------------------------------------------------------------------
// Banded attention for one window (FP16 q/k/v): acc[8] = softmax(q.K^T) @ V.
// QK dot via v_dot2_f32_f16 (2 MACs/inst, f32 accum); q-scale applied
// post-reduce (algebraically identical). Per-j unrolled; interior fast path.
// ---------------------------------------------------------------------------
template<int W>
__device__ __forceinline__ void banded_acc(const unsigned short* __restrict__ q,
                                           const unsigned short* __restrict__ k,
                                           const unsigned short* __restrict__ v,
                                           long long rowbase, int t, float* acc)
{
  constexpr int NJ = 2 * W + 1;
  const float SC128 = 0.08838834764831845f;
  const bool interior = (t >= W) && (t < 480 - W);

  half8v qh = *(const half8v*)(q + rowbase);

  const unsigned short* kbase = k + rowbase - (long long)W * 512;
  const unsigned short* vbase = v + rowbase - (long long)W * 512;

  float s[NJ];
  if (interior) {
    #pragma unroll
    for (int j = 0; j < NJ; j++) {
      half8v kh = *(const half8v*)(kbase + (long long)j * 512);
      float d = 0.f;
      #pragma unroll
      for (int pp = 0; pp < 4; pp++) {
        half2v qa = {qh[2 * pp], qh[2 * pp + 1]};
        half2v ka = {kh[2 * pp], kh[2 * pp + 1]};
        d = __builtin_amdgcn_fdot2(qa, ka, d, false);
      }
      d += __shfl_xor(d, 1); d += __shfl_xor(d, 2);
      d += __shfl_xor(d, 4); d += __shfl_xor(d, 8);
      s[j] = d * SC128;
    }
  } else {
    #pragma unroll
    for (int j = 0; j < NJ; j++) {
      int tt = t + j - W;
      float d = -1e30f;
      if ((unsigned)tt < 480u) {
        half8v kh = *(const half8v*)(kbase + (long long)j * 512);
        d = 0.f;
        #pragma unroll
        for (int pp = 0; pp < 4; pp++) {
          half2v qa = {qh[2 * pp], qh[2 * pp + 1]};
          half2v ka = {kh[2 * pp], kh[2 * pp + 1]};
          d = __builtin_amdgcn_fdot2(qa, ka, d, false);
        }
        d += __shfl_xor(d, 1); d += __shfl_xor(d, 2);
        d += __shfl_xor(d, 4); d += __shfl_xor(d, 8);
        d *= SC128;
      }
      s[j] = d;
    }
  }

  float m = s[0];
  #pragma unroll
  for (int j = 1; j < NJ; j++) m = fmaxf(m, s[j]);
  float sum = 0.f;
  #pragma unroll
  for (int j = 0; j < NJ; j++) { s[j] = expf(s[j] - m); sum += s[j]; }
  float inv = 1.f / sum;

  if (interior) {
    #pragma unroll
    for (int j = 0; j < NJ; j++) {
      half8v vh = *(const half8v*)(vbase + (long long)j * 512);
      float p = s[j] * inv;
      #pragma unroll
      for (int i = 0; i < 8; i++) acc[i] = fmaf(p, (float)vh[i], acc[i]);
    }
  } else {
    #pragma unroll
    for (int j = 0; j < NJ; j++) {
      int tt = t + j - W;
      if ((unsigned)tt < 480u) {
        half8v vh = *(const half8v*)(vbase + (long long)j * 512);
        float p = s[j] * inv;
        #pragma unroll
        for (int i = 0; i < 8; i++) acc[i] = fmaf(p, (float)vh[i], acc[i]);
      }
    }
  }
}

// ---------------------------------------------------------------------------
// Pair-fused sliding-window attention + residual-LN, XCD-chunked swizzle.
// q/k/v are FP16 (written by the projection's fast epilogue, omode bit 32).
// mode 0: MS = sum;  mode 2: outB = f2b((MS + sum) * 0.25)
// ---------------------------------------------------------------------------
template<int W1, int W2>
__global__ void slide_attn2_ln(const unsigned short* __restrict__ q1,
                               const unsigned short* __restrict__ k1,
                               const unsigned short* __restrict__ v1,
                               const unsigned short* __restrict__ q2,
                               const unsigned short* __restrict__ k2,
                               const unsigned short* __restrict__ v2,
                               const float* __restrict__ Afp,
                               const float* __restrict__ gb1,
                               const float* __restrict__ gb2,
                               float* __restrict__ MS,
                               unsigned short* __restrict__ outB, int mode)
{
  // bijective chunked swizzle (nwg divisible by 8)
  int nwg = gridDim.x;
  int orig = blockIdx.x;
  int blk = (orig & 7) * (nwg >> 3) + (orig >> 3);
  int wid = blk * (blockDim.x >> 6) + (threadIdx.x >> 6);
  if (wid >= 32 * 480) return;
  int lane = threadIdx.x & 63;
  int t = wid % 480;
  long long rowbase = (long long)wid * 512 + lane * 8;

  float arow[8];
  #pragma unroll
  for (int i = 0; i < 8; i++) arow[i] = Afp[rowbase + i];

  float msum[8] = {};
  // ---- window 1 ----
  {
    float acc[8] = {};
    banded_acc<W1>(q1, k1, v1, rowbase, t, acc);
    float x[8]; float ss = 0.f;
    #pragma unroll
    for (int i = 0; i < 8; i++) { x[i] = arow[i] + acc[i]; ss += x[i]; }
    ss = wave_sum(ss);
    float mean = ss * (1.f / DM);
    float vs = 0.f;
    #pragma unroll
    for (int i = 0; i < 8; i++) { float d = x[i] - mean; vs += d * d; }
    vs = wave_sum(vs);
    float rstd = rsqrtf(vs * (1.f / DM) + 1e-5f);
    #pragma unroll
    for (int i = 0; i < 8; i++) {
      int d = lane * 8 + i;
      msum[i] += (x[i] - mean) * rstd * gb1[d] + gb1[DM + d];
    }
  }
  // ---- window 2 ----
  {
    float acc[8] = {};
    banded_acc<W2>(q2, k2, v2, rowbase, t, acc);
    float x[8]; float ss = 0.f;
    #pragma unroll
    for (int i = 0; i < 8; i++) { x[i] = arow[i] + acc[i]; ss += x[i]; }
    ss = wave_sum(ss);
    float mean = ss * (1.f / DM);
    float vs = 0.f;
    #pragma unroll
    for (int i = 0; i < 8; i++) { float d = x[i] - mean; vs += d * d; }
    vs = wave_sum(vs);
    float rstd = rsqrtf(vs * (1.f / DM) + 1e-5f);
    #pragma unroll
    for (int i = 0; i < 8; i++) {
      int d = lane * 8 + i;
      msum[i] += (x[i] - mean) * rstd * gb2[d] + gb2[DM + d];
    }
  }

  if (mode == 0) {
    #pragma unroll
    for (int i = 0; i < 8; i++) MS[rowbase + i] = msum[i];
  } else {
    #pragma unroll
    for (int i = 0; i < 8; i++)
      outB[rowbase + i] = f2b((MS[rowbase + i] + msum[i]) * 0.25f);
  }
}

// ---------------------------------------------------------------------------
// mean over time, two-phase. part[b][g][d] = sum_{t in g} fused[b][t][d]
__global__ void mean_part(const float* __restrict__ fused, float* __restrict__ part)
{
  int b = blockIdx.x, g = blockIdx.y, d = threadIdx.x;
  float s0 = 0.f, s1 = 0.f, s2 = 0.f;
  int t0 = g * 30;
  for (int t = t0; t < t0 + 30; t += 3) {
    s0 += fused[(long long)(b * 480 + t) * 512 + d];
    s1 += fused[(long long)(b * 480 + t + 1) * 512 + d];
    s2 += fused[(long long)(b * 480 + t + 2) * 512 + d];
  }
  part[(long long)(b * 16 + g) * 512 + d] = s0 + s1 + s2;
}
// comb_b[b][0:512] = mean fused; comb_b[b][512:1024] = mean qstf. bf16 out.
__global__ void mean_fin(const float* __restrict__ part, const float* __restrict__ qstf,
                         unsigned short* __restrict__ comb)
{
  int b = blockIdx.x, d = threadIdx.x;
  float s = 0.f;
  #pragma unroll
  for (int g = 0; g < 16; g++) s += part[(long long)(b * 16 + g) * 512 + d];
  comb[b * 1024 + d] = f2b(s * (1.f / 480.f));
  float s2 = 0.f;
  for (int l = 0; l < 20; l += 2) {
    s2 += qstf[(long long)(b * 20 + l) * 512 + d];
    s2 += qstf[(long long)(b * 20 + l + 1) * 512 + d];
  }
  comb[b * 1024 + 512 + d] = f2b(s2 * (1.f / 20.f));
}

// fp32 [M][K] -> bf16 [M][Kp] (zero pad), with scale
__global__ void conv_act(const float* __restrict__ X, unsigned short* __restrict__ Xb,
                         int M, int K, int Kp, float sc)
{
  long long idx = (long long)blockIdx.x * 256 + threadIdx.x;
  if (idx >= (long long)M * Kp) return;
  int m = idx / Kp, k2 = idx - (long long)m * Kp;
  float v = (k2 < K) ? X[(long long)m * K + k2] * sc : 0.f;
  Xb[idx] = f2b(v);
}

// ---------------------------------------------------------------------------
// Batched weight transpose+convert: one launch handles many matrices.
// ---------------------------------------------------------------------------
struct TcD { const float* src; unsigned short* dst; int K, Kp, N, ldw; };
struct TcTab { TcD d[18]; int n; };

__global__ void transconv_all(TcTab tab)
{
  if ((int)blockIdx.z >= tab.n) return;
  TcD tc = tab.d[blockIdx.z];
  int k0 = blockIdx.x * 32, n0 = blockIdx.y * 32;
  if (k0 >= tc.Kp || n0 >= tc.N) return;
  __shared__ float T[32][33];
  int tx = threadIdx.x & 31, ty = threadIdx.x >> 5;
  #pragma unroll
  for (int r = 0; r < 4; r++) {
    int kk = k0 + ty + r * 8, n = n0 + tx;
    T[ty + r * 8][tx] = (kk < tc.K && n < tc.N) ? tc.src[(long long)kk * tc.ldw + n] : 0.f;
  }
  __syncthreads();
  #pragma unroll
  for (int r = 0; r < 4; r++) {
    int n = n0 + ty + r * 8, kk = k0 + tx;
    if (n < tc.N && kk < tc.Kp) tc.dst[(long long)n * tc.Kp + kk] = f2b(T[tx][ty + r * 8]);
  }
}

// ---------------------------------------------------------------------------

extern "C" void kernel_launch(void* const* d_in, const int* in_sizes, int n_in,
                              void* d_out, int out_size, void* d_ws, size_t ws_size,
                              hipStream_t stream)
{
  int ii = 0;
  const float* audio      = (const float*)d_in[ii++]; // 0
  const float* question   = (const float*)d_in[ii++];
  const float* audio_fc_w = (const float*)d_in[ii++];
  const float* audio_fc_b = (const float*)d_in[ii++];
  const float* qst_fc_w   = (const float*)d_in[ii++];
  const float* qst_fc_b   = (const float*)d_in[ii++]; // 5
  const float* attnq_in_w = (const float*)d_in[ii++];
  const float* attnq_in_b = (const float*)d_in[ii++];
  const float* attnq_out_w= (const float*)d_in[ii++];
  const float* attnq_out_b= (const float*)d_in[ii++];
  const float* qq_lin1_w  = (const float*)d_in[ii++]; // 10
  const float* qq_lin1_b  = (const float*)d_in[ii++];
  const float* qq_lin2_w  = (const float*)d_in[ii++];
  const float* qq_lin2_b  = (const float*)d_in[ii++];
  const float* qq_ln      = (const float*)d_in[ii++];
  const float* sa_in_w    = (const float*)d_in[ii++]; // 15
  const float* sa_in_b    = (const float*)d_in[ii++];
  const float* sa_out_w   = (const float*)d_in[ii++];
  const float* sa_out_b   = (const float*)d_in[ii++];
  const float* cm_in_w    = (const float*)d_in[ii++];
  const float* cm_in_b    = (const float*)d_in[ii++]; // 20
  const float* cm_out_w   = (const float*)d_in[ii++];
  const float* cm_out_b   = (const float*)d_in[ii++];
  const float* ff1_w      = (const float*)d_in[ii++];
  const float* ff1_b      = (const float*)d_in[ii++];
  const float* ff2_w      = (const float*)d_in[ii++]; // 25
  const float* ff2_b      = (const float*)d_in[ii++];
  const float* ln1        = (const float*)d_in[ii++];
  const float* ln2        = (const float*)d_in[ii++];
  const float* ms_qkv_w   = (const float*)d_in[ii++];
  const float* ms_qkv_b   = (const float*)d_in[ii++]; // 30
  const float* ms_ln      = (const float*)d_in[ii++];
  const float* msl_w      = (const float*)d_in[ii++];
  const float* msl_b      = (const float*)d_in[ii++];
  const float* ms_norm    = (const float*)d_in[ii++];
  const float* qa_in_w    = (const float*)d_in[ii++]; // 35
  const float* qa_in_b    = (const float*)d_in[ii++];
  const float* qa_out_w   = (const float*)d_in[ii++];
  const float* qa_out_b   = (const float*)d_in[ii++];
  const float* qa_ff1_w   = (const float*)d_in[ii++];
  const float* qa_ff1_b   = (const float*)d_in[ii++]; // 40
  const float* qa_ff2_w   = (const float*)d_in[ii++];
  const float* qa_ff2_b   = (const float*)d_in[ii++];
  const float* qa_ln1     = (const float*)d_in[ii++];
  const float* qa_ln2     = (const float*)d_in[ii++];
  const float* fc1_w      = (const float*)d_in[ii++]; // 45
  const float* fc1_b      = (const float*)d_in[ii++];
  const float* fc2_w      = (const float*)d_in[ii++];
  const float* fc2_b      = (const float*)d_in[ii++];
  const float* pred_w     = (const float*)d_in[ii++];
  const float* pred_b     = (const float*)d_in[ii++]; // 50
  (void)in_sizes; (void)n_in; (void)out_size; (void)ws_size;

  // ---- arena (~226.7 MB; bf16 B1..B3 immediately followed by P0,P1 so the
  //      six stage-5 QKV segments are one contiguous stride-NB run) ----
  char* base = (char*)d_ws;
  size_t off = 0;
  auto alloc_f = [&](size_t n) {
    float* p = (float*)(base + off);
    off += ((n * 4 + 255) & ~(size_t)255);
    return p;
  };
  auto alloc_h = [&](size_t n) {
    unsigned short* p = (unsigned short*)(base + off);
    off += ((n * 2 + 255) & ~(size_t)255);
    return p;
  };
  const size_t NB = (size_t)15360 * 512;
  // fp32 NB buffers
  float* A  = alloc_f(NB);
  float* MS = alloc_f(NB);
  // bf16 NB buffers (contiguous run: B1,B2,B3, then P0/P1 fp32 right after)
  unsigned short* Ab = alloc_h(NB);
  unsigned short* B1 = alloc_h(NB);
  unsigned short* B2 = alloc_h(NB);
  unsigned short* B3 = alloc_h(NB);
  float* P0 = alloc_f(NB);
  float* P1 = alloc_f(NB);
  // small fp32
  float* SBq = alloc_f((size_t)61440 * 20);   // narrow (L=20) scores; later: mean partials
  float* QF = alloc_f((size_t)640 * 512);
  float* q0 = alloc_f((size_t)640 * 512);     // q0,q1,q2 contiguous
  float* q1 = alloc_f((size_t)640 * 512);
  float* q2 = alloc_f((size_t)640 * 512);
  float* t1 = alloc_f((size_t)640 * 512);
  // small bf16
  unsigned short* COMBb = alloc_h((size_t)32 * 1024);
  unsigned short* C1b   = alloc_h((size_t)32 * 512);
  unsigned short* C2b   = alloc_h((size_t)32 * 256);
  unsigned short* QGb = alloc_h((size_t)640 * 512);
  unsigned short* QFb = alloc_h((size_t)640 * 512);
  unsigned short* audio_b = alloc_h((size_t)15360 * 128);
  unsigned short* quest_b = alloc_h((size_t)640 * 320);
  unsigned short* wb = alloc_h((size_t)10272000);
  (void)alloc_h(131072); // 256KB tail slack for staging overreads

  // aliases (lifetime-checked):
  float* SB = P1;                             // dense scores (32 x 480 x 480 f32)
  unsigned short* SBb3 = (unsigned short*)MS; // stage-3 bf16 probs (MS born in stage 5)
  unsigned short* SBb7 = (unsigned short*)A;  // stage-7 bf16 probs (A dead after stage 6 proj)
  float* PART = SBq;                          // stage-8 mean partials (SBq dead after stage 6)
  unsigned short* QB2 = (unsigned short*)P0;  // stage-5 window-B QKV (== B3 + NB)

  const float SC128 = 0.08838834764831845f;
  const float SC512 = 0.04419417382415922f;

  auto mf = [&](const unsigned short* Am, const unsigned short* Btm, const float* bias,
                float* Cm, unsigned short* Cbm, int M, int N, int K,
                int lda, int ldb, int ldc, long long aB, long long bB, long long cB,
                int Z, float preS, float postS, int act, int omode) {
    if (N <= 512) {
      dim3 g((N + 63) / 64, (M + 127) / 128, Z);
      gemm_mfma<2><<<g, 256, 0, stream>>>(Am, Btm, bias, Cm, Cbm, M, N, K, lda, ldb, ldc,
                                          aB, bB, cB, preS, postS, act, omode);
    } else {
      dim3 g((N + 127) / 128, (M + 127) / 128, Z);
      gemm_mfma<4><<<g, 256, 0, stream>>>(Am, Btm, bias, Cm, Cbm, M, N, K, lda, ldb, ldc,
                                          aB, bB, cB, preS, postS, act, omode);
    }
  };
  auto gemm = [&](const float* Am, const float* Bm, const float* bias, float* Cm,
                  unsigned short* Cbm,
                  int M, int N, int K, int lda, int ldb, int ldc,
                  long long aB, long long aH, long long bB, long long bH,
                  long long cB, long long cH, int Z, int nh, bool tB,
                  float preS, float postS, int act) {
    dim3 g((N + 63) / 64, (M + 63) / 64, Z);
    gemm_f32<<<g, 256, 0, stream>>>(Am, Bm, bias, Cm, Cbm, M, N, K, lda, ldb, ldc,
                                    aB, aH, bB, bH, cB, cH, nh, tB ? 1 : 0, preS, postS, act);
  };
  auto softmax = [&](float* S, unsigned short* Sb, int R, int L, int ld) {
    softmax_rows<<<dim3((R + 3) / 4), 256, 0, stream>>>(S, Sb, R, L, ld);
  };
  auto ln = [&](const float* a, const float* b, const float* c, const float* gb,
                float* outp, unsigned short* outbp, int rows, int accum) {
    ln_rows<<<dim3((rows + 3) / 4), 256, 0, stream>>>(a, b, c, gb, outp, outbp, rows, accum);
  };
  auto dot = [&](const unsigned short* Am, const unsigned short* Wtm, const float* bias,
                 float* Cf, unsigned short* Cb, int M, int N, int K, int act) {
    dot_gemm<<<dim3((M * N + 3) / 4), 256, 0, stream>>>(Am, Wtm, bias, Cf, Cb, M, N, K, act);
  };

  // ---- weight buffer layout ----
  unsigned short* wp = wb;
  auto WT = [&](size_t n) { unsigned short* r = wp; wp += n; return r; };
  unsigned short* wt_audio   = WT(512 * 128);
  unsigned short* wt_qst     = WT(512 * 320);
  unsigned short* wt_aq_in   = WT(3 * 262144);
  unsigned short* wt_aq_out  = WT(262144);
  unsigned short* wt_qq1     = WT(262144);
  unsigned short* wt_qq2     = WT(262144);
  unsigned short* wt_cm_in   = WT(3 * 262144);
  unsigned short* wt_cm_out  = WT(262144);
  unsigned short* wt_sa_in   = WT(3 * 262144);
  unsigned short* wt_sa_out  = WT(262144);
  unsigned short* wt_ff1     = WT(262144);
  unsigned short* wt_ff2     = WT(262144);
  unsigned short* wt_ms      = WT(12 * 262144);
  unsigned short* wt_msl     = WT(262144);
  unsigned short* wt_qa_in   = WT(3 * 262144);
  unsigned short* wt_qa_out  = WT(262144);
  unsigned short* wt_qa_ff1  = WT(262144);
  unsigned short* wt_qa_ff2  = WT(262144);
  unsigned short* wt_fc1     = WT(512 * 1024);
  unsigned short* wt_fc2     = WT(256 * 512);
  unsigned short* wt_pred    = WT(828 * 256);

  // ---- batched weight conversion: 3 launches ----
  {
    TcTab tA1 = {}; int n = 0;
    for (int z = 0; z < 3; z++)
      tA1.d[n++] = {attnq_in_w + z * 512, wt_aq_in + (size_t)z * 262144, 512, 512, 512, 1536};
    tA1.d[n++] = {attnq_out_w, wt_aq_out, 512, 512, 512, 512};
    tA1.d[n++] = {qq_lin1_w, wt_qq1, 512, 512, 512, 512};
    tA1.d[n++] = {qq_lin2_w, wt_qq2, 512, 512, 512, 512};
    for (int z = 0; z < 3; z++)
      tA1.d[n++] = {cm_in_w + z * 512, wt_cm_in + (size_t)z * 262144, 512, 512, 512, 1536};
    tA1.d[n++] = {cm_out_w, wt_cm_out, 512, 512, 512, 512};
    for (int z = 0; z < 3; z++)
      tA1.d[n++] = {sa_in_w + z * 512, wt_sa_in + (size_t)z * 262144, 512, 512, 512, 1536};
    tA1.d[n++] = {sa_out_w, wt_sa_out, 512, 512, 512, 512};
    tA1.d[n++] = {ff1_w, wt_ff1, 512, 512, 512, 512};
    tA1.d[n++] = {ff2_w, wt_ff2, 512, 512, 512, 512};
    for (int m = 0; m < 2; m++)
      tA1.d[n++] = {ms_qkv_w + (size_t)m * 262144, wt_ms + (size_t)m * 262144, 512, 512, 512, 512};
    tA1.n = n;  // 18
    transconv_all<<<dim3(16, 16, 18), 256, 0, stream>>>(tA1);

    TcTab tA2 = {}; n = 0;
    for (int m = 2; m < 12; m++)
      tA2.d[n++] = {ms_qkv_w + (size_t)m * 262144, wt_ms + (size_t)m * 262144, 512, 512, 512, 512};
    tA2.d[n++] = {msl_w, wt_msl, 512, 512, 512, 512};
    for (int z = 0; z < 3; z++)
      tA2.d[n++] = {qa_in_w + (size_t)3 * 512 * 1536 + z * 512, wt_qa_in + (size_t)z * 262144, 512, 512, 512, 1536};
    tA2.d[n++] = {qa_out_w + (size_t)3 * 262144, wt_qa_out, 512, 512, 512, 512};
    tA2.d[n++] = {qa_ff1_w + (size_t)3 * 262144, wt_qa_ff1, 512, 512, 512, 512};
    tA2.d[n++] = {qa_ff2_w + (size_t)3 * 262144, wt_qa_ff2, 512, 512, 512, 512};
    tA2.n = n;  // 17
    transconv_all<<<dim3(16, 16, 17), 256, 0, stream>>>(tA2);

    TcTab tB = {}; int n2 = 0;
    tB.d[n2++] = {audio_fc_w, wt_audio, 128, 128, 512, 512};
    tB.d[n2++] = {qst_fc_w, wt_qst, 300, 320, 512, 512};
    tB.d[n2++] = {fc1_w, wt_fc1, 1024, 1024, 512, 512};
    tB.d[n2++] = {fc2_w, wt_fc2, 512, 512, 256, 256};
    tB.d[n2++] = {pred_w, wt_pred, 256, 256, 828, 828};
    tB.n = n2;  // 5
    transconv_all<<<dim3(32, 26, 5), 256, 0, stream>>>(tB);
  }

  // ---- activation input conversion ----
  conv_act<<<dim3((15360 * 128 + 255) / 256), 256, 0, stream>>>(audio, audio_b, 15360, 128, 128, 1.f);
  conv_act<<<dim3((640 * 320 + 255) / 256), 256, 0, stream>>>(question, quest_b, 640, 300, 320, 1.f);

  // ---- stage 0: input projections ----
  mf(audio_b, wt_audio, audio_fc_b, A, Ab, 15360, 512, 128, 128, 128, 512, 0, 0, 0, 1, 1.f, 1.f, 0, 3);
  mf(quest_b, wt_qst, qst_fc_b, nullptr, QGb, 640, 512, 320, 320, 320, 512, 0, 0, 0, 1, 1.f, 1.f, 0, 2);

  // ---- stage 1: question self-attn (h=4, fused QKV) + qst_query_block -> QF ----
  mf(QGb, wt_aq_in, attnq_in_b, q0, nullptr, 640, 1536, 512, 512, 512, 512,
     0, 0, (long long)640 * 512, 1, 1.f, 1.f, 0, 1 | 16);
  gemm(q0, q1, nullptr, SBq, nullptr, 20, 20, 128, 512, 512, 20,
       20 * 512, 128, 20 * 512, 128, 1600, 400, 128, 4, true, SC128, 1.f, 0);
  softmax(SBq, nullptr, 2560, 20, 20);
  gemm(SBq, q2, nullptr, nullptr, B1, 20, 128, 20, 20, 512, 512,
       1600, 400, 20 * 512, 128, 20 * 512, 128, 128, 4, false, 1.f, 1.f, 0);
  mf(B1, wt_aq_out, attnq_out_b, t1, B2, 640, 512, 512, 512, 512, 512, 0, 0, 0, 1, 1.f, 1.f, 0, 3);
  mf(B2, wt_qq1, qq_lin1_b, nullptr, B1, 640, 512, 512, 512, 512, 512, 0, 0, 0, 1, 1.f, 1.f, 1, 2);
  mf(B1, wt_qq2, qq_lin2_b, q0, nullptr, 640, 512, 512, 512, 512, 512, 0, 0, 0, 1, 1.f, 1.f, 0, 1);
  ln(t1, q0, nullptr, qq_ln, QF, QFb, 640, 0);

  // ---- stage 2: s1 = cross-attn(A, QG, QG) h=1 -> P0 ----
  mf(Ab,  wt_cm_in,              cm_in_b + 0,    nullptr, B1, 15360, 512, 512, 512, 512, 512, 0, 0, 0, 1, 1.f, 1.f, 0, 2);
  mf(QGb, wt_cm_in + 262144,     cm_in_b + 512,  nullptr, B3, 640, 512, 512, 512, 512, 512, 0, 0, 0, 1, 1.f, 1.f, 0, 2);
  mf(QGb, wt_cm_in + 2 * 262144, cm_in_b + 1024, q2, nullptr, 640, 512, 512, 512, 512, 512, 0, 0, 0, 1, 1.f, 1.f, 0, 1);
  mf(B1, B3, nullptr, SBq, nullptr, 480, 20, 512, 512, 512, 20,
     480 * 512, 20 * 512, 9600, 32, SC512, 1.f, 0, 1);
  softmax(SBq, nullptr, 15360, 20, 20);
  gemm(SBq, q2, nullptr, nullptr, B1, 480, 512, 20, 20, 512, 512,
       9600, 0, 20 * 512, 0, 480 * 512, 0, 32, 1, false, 1.f, 1.f, 0);
  mf(B1, wt_cm_out, cm_out_b, P0, nullptr, 15360, 512, 512, 512, 512, 512, 0, 0, 0, 1, 1.f, 1.f, 0, 1);

  // ---- stage 3: s2 = dense self-attn(A) h=1, accumulate into P0 ----
  mf(Ab, wt_sa_in, sa_in_b, nullptr, B1, 15360, 1024, 512, 512, 512, 512,
     0, 0, (long long)NB, 1, 1.f, 1.f, 0, 2 | 16);   // Q->B1, K->B2
  mf(Ab, wt_sa_in + 2 * 262144, sa_in_b + 1024, nullptr, B3, 15360, 512, 512, 512, 512, 512, 0, 0, 0, 1, 1.f, 1.f, 0, 4);
  mf(B1, B2, nullptr, SB, nullptr, 480, 480, 512, 512, 512, 480,
     480 * 512, 480 * 512, 480 * 480, 32, SC512, 1.f, 0, 1);
  softmax(SB, SBb3, 15360, 480, 480);
  mf(SBb3, B3, nullptr, nullptr, B1, 480, 512, 480, 480, 480, 512,
     480 * 480, 512 * 480, 480 * 512, 32, 1.f, 1.f, 0, 2);
  mf(B1, wt_sa_out, sa_out_b, P0, nullptr, 15360, 512, 512, 512, 512, 512, 0, 0, 0, 1, 1.f, 1.f, 0, 9);  // P0 += s2

  // ---- stage 4: x = LN(A + s1+s2); audio_feat = LN(x + FFN(x)) -> A ----
  ln(A, P0, nullptr, ln1, P1, B1, 15360, 0);
  mf(B1, wt_ff1, ff1_b, nullptr, B2, 15360, 512, 512, 512, 512, 512, 0, 0, 0, 1, 1.f, 1.f, 1, 2);
  mf(B2, wt_ff2, ff2_b, P0, nullptr, 15360, 512, 512, 512, 512, 512, 0, 0, 0, 1, 1.f, 1.f, 0, 1);
  ln(P1, P0, nullptr, ln2, A, Ab, 15360, 0);

  // ---- stage 5: multi-window sliding attention (pair-fused, merged QKV, fp16) ----
  // pair p: ONE N=3072 projection (fp16 epilogue) -> 6 contiguous NB segments
  for (int p = 0; p < 2; p++) {
    mf(Ab, wt_ms + (size_t)(p * 6) * 262144, ms_qkv_b + (size_t)(p * 6) * 512,
       nullptr, B1, 15360, 3072, 512, 512, 512, 512,
       0, 0, (long long)NB, 1, 1.f, 1.f, 0, 2 | 16 | 32);
    dim3 sg((32 * 480) / 4);
    if (p == 0)
      slide_attn2_ln<2, 4><<<sg, 256, 0, stream>>>(
          B1, B2, B3, QB2, QB2 + NB, QB2 + 2 * NB, A,
          ms_ln + 0, ms_ln + 1024, MS, nullptr, 0);
    else
      slide_attn2_ln<6, 12><<<sg, 256, 0, stream>>>(
          B1, B2, B3, QB2, QB2 + NB, QB2 + 2 * NB, A,
          ms_ln + 2048, ms_ln + 3072, MS, Ab, 2);
  }
  // Ab = bf16(0.25 * (ln0+ln1+ln2+ln3))  (multi-scale avg)
  mf(Ab, wt_msl, msl_b, P0, nullptr, 15360, 512, 512, 512, 512, 512, 0, 0, 0, 1, 1.f, 1.f, 0, 1);
  ln(A, P0, nullptr, ms_norm, A, Ab, 15360, 0);   // audio_feat

  // ---- stage 6: question-queried attn (h=4) + qq block -> av (MS f32, Ab bf16) ----
  mf(Ab,  wt_aq_in, attnq_in_b, P0, nullptr, 15360, 512, 512, 512, 512, 512, 0, 0, 0, 1, 1.f, 1.f, 0, 1);
  mf(QFb, wt_aq_in + 262144, attnq_in_b + 512, q1, nullptr, 640, 1024, 512, 512, 512, 512,
     0, 0, (long long)640 * 512, 1, 1.f, 1.f, 0, 1 | 16);  // K->q1, V->q2
  gemm(P0, q1, nullptr, SBq, nullptr, 480, 20, 128, 512, 512, 20,
       480 * 512, 128, 20 * 512, 128, 38400, 9600, 128, 4, true, SC128, 1.f, 0);
  softmax(SBq, nullptr, 61440, 20, 20);
  gemm(SBq, q2, nullptr, nullptr, B1, 480, 128, 20, 20, 512, 512,
       38400, 9600, 20 * 512, 128, 480 * 512, 128, 128, 4, false, 1.f, 1.f, 0);
  mf(B1, wt_aq_out, attnq_out_b, P0, B2, 15360, 512, 512, 512, 512, 512, 0, 0, 0, 1, 1.f, 1.f, 0, 3);
  mf(B2, wt_qq1, qq_lin1_b, nullptr, B3, 15360, 512, 512, 512, 512, 512, 0, 0, 0, 1, 1.f, 1.f, 1, 2);
  mf(B3, wt_qq2, qq_lin2_b, P1, nullptr, 15360, 512, 512, 512, 512, 512, 0, 0, 0, 1, 1.f, 1.f, 0, 1);
  ln(P0, P1, nullptr, qq_ln, MS, Ab, 15360, 0);   // av

  // ---- stage 7: Encoder_QA layer 3 (h=1), dense MFMA attention on av ----
  const float* qa_inb3 = qa_in_b + (size_t)3 * 1536;
  mf(Ab, wt_qa_in, qa_inb3, nullptr, B1, 15360, 1024, 512, 512, 512, 512,
     0, 0, (long long)NB, 1, 1.f, 1.f, 0, 2 | 16);   // Q->B1, K->B2
  mf(Ab, wt_qa_in + 2 * 262144, qa_inb3 + 1024, nullptr, B3, 15360, 512, 512, 512, 512, 512, 0, 0, 0, 1, 1.f, 1.f, 0, 4);
  mf(B1, B2, nullptr, SB, nullptr, 480, 480, 512, 512, 512, 480,
     480 * 512, 480 * 512, 480 * 480, 32, SC512, 1.f, 0, 1);
  softmax(SB, SBb7, 15360, 480, 480);
  mf(SBb7, B3, nullptr, nullptr, B1, 480, 512, 480, 480, 480, 512,
     480 * 480, 512 * 480, 480 * 512, 32, 1.f, 1.f, 0, 2);
  mf(B1, wt_qa_out, qa_out_b + 3 * 512, P0, nullptr, 15360, 512, 512, 512, 512, 512, 0, 0, 0, 1, 1.f, 1.f, 0, 1);
  ln(MS, P0, nullptr, qa_ln1 + 3 * 1024, P1, B1, 15360, 0);
  mf(B1, wt_qa_ff1, qa_ff1_b + 3 * 512, nullptr, B2, 15360, 512, 512, 512, 512, 512, 0, 0, 0, 1, 1.f, 1.f, 1, 2);
  mf(B2, wt_qa_ff2, qa_ff2_b + 3 * 512, P0, nullptr, 15360, 512, 512, 512, 512, 512, 0, 0, 0, 1, 1.f, 1.f, 0, 1);
  ln(P1, P0, nullptr, qa_ln2 + 3 * 1024, MS, nullptr, 15360, 0);  // fused -> MS

  // ---- stage 8: head (wave-dot, bf16) ----
  mean_part<<<dim3(32, 16), 512, 0, stream>>>(MS, PART);
  mean_fin<<<32, 512, 0, stream>>>(PART, QF, COMBb);
  dot(COMBb, wt_fc1, fc1_b, nullptr, C1b, 32, 512, 1024, 2);
  dot(C1b, wt_fc2, fc2_b, nullptr, C2b, 32, 256, 512, 2);
  dot(C2b, wt_pred, pred_b, (float*)d_out, nullptr, 32, 828, 256, 0);
}

// Round 19
// 1403.929 us; speedup vs baseline: 1.0169x; 1.0169x over previous
//
#include <hip/hip_runtime.h>
#include <math.h>

#define DM 512

typedef __attribute__((ext_vector_type(8))) short short8v;
typedef __attribute__((ext_vector_type(4))) float floatx4;

__device__ inline unsigned short f2b(float x){
  unsigned u = __builtin_bit_cast(unsigned, x);
  u += 0x7fffu + ((u >> 16) & 1u);
  return (unsigned short)(u >> 16);
}
__device__ inline float b2f(unsigned short h){
  unsigned u = ((unsigned)h) << 16;
  return __builtin_bit_cast(float, u);
}

__device__ inline float wave_sum(float v){
  #pragma unroll
  for (int off=32; off; off>>=1) v += __shfl_xor(v, off);
  return v;
}
__device__ inline float wave_max(float v){
  #pragma unroll
  for (int off=32; off; off>>=1) v = fmaxf(v, __shfl_xor(v, off));
  return v;
}

__device__ inline void gload16(const unsigned short* g, unsigned short* l){
  __builtin_amdgcn_global_load_lds(
      (const __attribute__((address_space(1))) unsigned int*)g,
      (__attribute__((address_space(3))) unsigned int*)l, 16, 0, 0);
}

// ---------------------------------------------------------------------------
// bf16 MFMA GEMM — T4 counted-vmcnt 3-buffer pipeline (depth 2), T2 swizzle.
// JF=4: 128x128 tile. JF=2: 128x64 tile (N<=512).
// Per iter: stage(buf[s+2]) ; compute(buf[s]) ; s_waitcnt vmcnt(NL) ;
// s_barrier ; sched_barrier(0).  NL = loads/stage (4 JF4, 3 JF2): leaves the
// just-issued tile s+2 loads in flight while guaranteeing tile s+1 (older)
// is resident. Tail iterations drain with vmcnt(0). WAR safe: buf (s+2)%3
// was last read at iter s-1's compute, with a barrier in between.
// T2: gload_lds dest LINEAR; global source column pre-permuted
// (slot ^= (row>>1)&3); compute reads slot (l>>4)^((row>>1)&3).
// omode bit0: fp32 C (bit3: accumulate). bit1: bf16 Cb. bit2: bf16 transposed
// per-batch-480. bit4: segmented-N (col>>9 picks segment; Z must be 1).
// bf16-only modes use an LDS-staged coalesced epilogue (full 64B lines).
// XCD-aware bijective swizzle (m204). Requires K % 32 == 0.
// ---------------------------------------------------------------------------
template<int JF>
__global__ __launch_bounds__(256) void gemm_mfma(
    const unsigned short* __restrict__ A, const unsigned short* __restrict__ Bt,
    const float* __restrict__ bias, float* __restrict__ C,
    unsigned short* __restrict__ Cb,
    int M, int N, int K, int lda, int ldb, int ldc,
    long long aB, long long bB, long long cB,
    float preS, float postS, int act, int omode)
{
  constexpr int ASZ = 4096;           // shorts per A buffer (128 x 32)
  constexpr int BSZ = JF * 1024;      // shorts per B buffer (JF*32 x 32)
  __shared__ alignas(16) unsigned short SM[3 * (ASZ + BSZ)];
  const int z = blockIdx.z;
  A += (long long)z * aB;
  Bt += (long long)z * bB;
  const int tid = threadIdx.x;
  const int w = tid >> 6, l = tid & 63;

  // XCD swizzle (bijective, m204); skip tiny grids
  int nwg = gridDim.x * gridDim.y;
  int orig = blockIdx.y * gridDim.x + blockIdx.x;
  int wgid = orig;
  if (nwg >= 16) {
    int qq = nwg >> 3, r = nwg & 7;
    int xcd = orig & 7, pos = orig >> 3;
    wgid = (xcd < r ? xcd * (qq + 1) : r * (qq + 1) + (xcd - r) * qq) + pos;
  }
  const int bx = wgid % gridDim.x, by = wgid / gridDim.x;
  const int m0 = by * 128, n0 = bx * (JF * 32);
  const int wm = (w >> 1) * 64, wn = (w & 1) * (JF * 16);
  const int srow = tid >> 2;            // 0..63 (local row this lane stages)
  const int scol = ((tid & 3) ^ ((srow >> 1) & 3)) * 8;  // T2 pre-swizzle

  floatx4 acc[4][JF];
  #pragma unroll
  for (int i = 0; i < 4; i++)
    #pragma unroll
    for (int j = 0; j < JF; j++) acc[i][j] = (floatx4)0.f;

  auto AsP = [&](int h) { return SM + h * ASZ; };
  auto BsP = [&](int h) { return SM + 3 * ASZ + h * BSZ; };

  auto stage = [&](int h, int kc) {
    gload16(A  + (long long)(m0 + srow)      * lda + kc + scol, AsP(h) + w * 512);
    gload16(A  + (long long)(m0 + 64 + srow) * lda + kc + scol, AsP(h) + 2048 + w * 512);
    gload16(Bt + (long long)(n0 + srow)      * ldb + kc + scol, BsP(h) + w * 512);
    if (JF == 4)
      gload16(Bt + (long long)(n0 + 64 + srow) * ldb + kc + scol, BsP(h) + 2048 + w * 512);
  };
  auto compute = [&](int h) {
    short8v a[4], b[JF];
    #pragma unroll
    for (int i = 0; i < 4; i++) {
      int rowA = wm + i * 16 + (l & 15);
      a[i] = *(const short8v*)&AsP(h)[rowA * 32 + (((l >> 4) ^ ((rowA >> 1) & 3)) * 8)];
    }
    #pragma unroll
    for (int j = 0; j < JF; j++) {
      int rowB = wn + j * 16 + (l & 15);
      b[j] = *(const short8v*)&BsP(h)[rowB * 32 + (((l >> 4) ^ ((rowB >> 1) & 3)) * 8)];
    }
    #pragma unroll
    for (int i = 0; i < 4; i++)
      #pragma unroll
      for (int j = 0; j < JF; j++)
        acc[i][j] = __builtin_amdgcn_mfma_f32_16x16x32_bf16(a[i], b[j], acc[i][j], 0, 0, 0);
  };
  auto wait_counted = [&]() {
    if (JF == 4) asm volatile("s_waitcnt vmcnt(4)" ::: "memory");
    else         asm volatile("s_waitcnt vmcnt(3)" ::: "memory");
  };

  // ---- T4 counted-vmcnt K-loop (half-tile = 32; K % 32 == 0) ----
  const int nsteps = K >> 5;
  stage(0, 0);
  if (nsteps > 1) {
    stage(1, 32);
    wait_counted();                     // tile 0 (older NL loads) resident
  } else {
    asm volatile("s_waitcnt vmcnt(0)" ::: "memory");
  }
  __builtin_amdgcn_s_barrier();
  __builtin_amdgcn_sched_barrier(0);
  for (int s = 0; s < nsteps; s++) {
    if (s + 2 < nsteps) stage((s + 2) % 3, (s + 2) << 5);
    compute(s % 3);
    if (s + 1 < nsteps) {
      if (s + 2 < nsteps) wait_counted();                       // tile s+1 done
      else asm volatile("s_waitcnt vmcnt(0)" ::: "memory");     // tail drain
      __builtin_amdgcn_s_barrier();
      __builtin_amdgcn_sched_barrier(0);
    }
  }

  // ---- fast epilogue: bf16-only output (optionally segmented) ----
  if (((omode & 13) == 0) && (omode & 2)) {
    float* E = (float*)SM;
    constexpr int HC = JF * 16;                 // cols per half (JF4:64, JF2:32)
    constexpr int NCH = (128 * HC) / (256 * 8); // 16B chunks per thread per half
    #pragma unroll
    for (int half = 0; half < 2; half++) {
      __syncthreads();
      if ((w & 1) == half) {
        #pragma unroll
        for (int i = 0; i < 4; i++)
          #pragma unroll
          for (int r = 0; r < 4; r++) {
            int row = wm + i * 16 + (l >> 4) * 4 + r;
            #pragma unroll
            for (int j = 0; j < JF; j++) {
              int colh = j * 16 + (l & 15);
              int colg = n0 + half * HC + colh;
              float v = preS * acc[i][j][r] + (bias ? bias[colg] : 0.f);
              if (act == 1) v = fmaxf(v, 0.f);
              E[row * HC + colh] = v * postS;
            }
          }
      }
      __syncthreads();
      #pragma unroll
      for (int c = 0; c < NCH; c++) {
        int eidx = (c * 256 + tid) * 8;
        int row = eidx / HC, colh = eidx % HC;
        int grow = m0 + row;
        int gcol0 = n0 + half * HC + colh;
        if (grow < M && gcol0 < N) {
          short8v o;
          #pragma unroll
          for (int e = 0; e < 8; e++) o[e] = (short)f2b(E[eidx + e]);
          long long sidx = (omode & 16)
              ? (long long)(gcol0 >> 9) * cB + (long long)grow * ldc + (gcol0 & 511)
              : (long long)z * cB + (long long)grow * ldc + gcol0;
          *(short8v*)(Cb + sidx) = o;
        }
      }
    }
    return;
  }

  // ---- scalar epilogue (fp32 / accumulate / transposed / dual modes) ----
  const long long coff = (long long)z * cB;
  #pragma unroll
  for (int i = 0; i < 4; i++) {
    #pragma unroll
    for (int r = 0; r < 4; r++) {
      int row = m0 + wm + i * 16 + (l >> 4) * 4 + r;
      if (row >= M) continue;
      #pragma unroll
      for (int j = 0; j < JF; j++) {
        int col = n0 + wn + j * 16 + (l & 15);
        if (col >= N) continue;
        float v = preS * acc[i][j][r] + (bias ? bias[col] : 0.f);
        if (act == 1) v = fmaxf(v, 0.f);
        v *= postS;
        long long sidx = (omode & 16)
            ? (long long)(col >> 9) * cB + (long long)row * ldc + (col & 511)
            : coff + (long long)row * ldc + col;
        if (omode & 1) C[sidx] = (omode & 8) ? (C[sidx] + v) : v;
        if (omode & 2) Cb[sidx] = f2b(v);
        if (omode & 4) {
          int bb = row / 480, t = row - bb * 480;
          Cb[(long long)bb * (512 * 480) + (long long)col * 480 + t] = f2b(v);
        }
      }
    }
  }
}

// ---------------------------------------------------------------------------
// fp32 vector GEMM + optional bf16 dual-write. C may be nullptr.
// ---------------------------------------------------------------------------
__global__ __launch_bounds__(256) void gemm_f32(
    const float* __restrict__ A, const float* __restrict__ B,
    const float* __restrict__ bias, float* __restrict__ C,
    unsigned short* __restrict__ Cb,
    int M, int N, int K, int lda, int ldb, int ldc,
    long long aB, long long aH, long long bB, long long bH,
    long long cB, long long cH, int nh, int transB,
    float preS, float postS, int act)
{
  int z = blockIdx.z;
  int bz = z / nh, hz = z - bz * nh;
  A += (long long)bz * aB + (long long)hz * aH;
  B += (long long)bz * bB + (long long)hz * bH;
  const long long coff = (long long)bz * cB + (long long)hz * cH;

  __shared__ float As[16][65];
  __shared__ float Bs[16][65];
  const int tid = threadIdx.x;
  const int m0 = blockIdx.y * 64, n0 = blockIdx.x * 64;
  const int tx = tid & 15, ty = tid >> 4;
  float acc[4][4] = {};

  for (int k0 = 0; k0 < K; k0 += 16) {
    int am = tid >> 2, ak = (tid & 3) * 4;
    #pragma unroll
    for (int i = 0; i < 4; i++) {
      int mm = m0 + am, kk = k0 + ak + i;
      As[ak + i][am] = (mm < M && kk < K) ? A[(long long)mm * lda + kk] : 0.f;
    }
    if (!transB) {
      #pragma unroll
      for (int r = 0; r < 4; r++) {
        int kr = (tid >> 6) + r * 4;
        int kk = k0 + kr, nn = n0 + (tid & 63);
        Bs[kr][tid & 63] = (kk < K && nn < N) ? B[(long long)kk * ldb + nn] : 0.f;
      }
    } else {
      int bn = tid >> 2, bk = (tid & 3) * 4;
      #pragma unroll
      for (int i = 0; i < 4; i++) {
        int nn = n0 + bn, kk = k0 + bk + i;
        Bs[bk + i][bn] = (nn < N && kk < K) ? B[(long long)nn * ldb + kk] : 0.f;
      }
    }
    __syncthreads();
    #pragma unroll
    for (int k = 0; k < 16; k++) {
      float a4[4], b4[4];
      #pragma unroll
      for (int i = 0; i < 4; i++) { a4[i] = As[k][ty * 4 + i]; b4[i] = Bs[k][tx * 4 + i]; }
      #pragma unroll
      for (int i = 0; i < 4; i++)
        #pragma unroll
        for (int j = 0; j < 4; j++)
          acc[i][j] = fmaf(a4[i], b4[j], acc[i][j]);
    }
    __syncthreads();
  }

  #pragma unroll
  for (int i = 0; i < 4; i++) {
    int mm = m0 + ty * 4 + i;
    if (mm >= M) continue;
    #pragma unroll
    for (int j = 0; j < 4; j++) {
      int nn = n0 + tx * 4 + j;
      if (nn >= N) continue;
      float v = preS * acc[i][j] + (bias ? bias[nn] : 0.f);
      if (act == 1) v = fmaxf(v, 0.f);
      else if (act == 2) v = tanhf(v);
      v *= postS;
      if (C)  C[coff + (long long)mm * ldc + nn] = v;
      if (Cb) Cb[coff + (long long)mm * ldc + nn] = f2b(v);
    }
  }
}

// ---------------------------------------------------------------------------
// Wave-per-output dot GEMM for tiny-M head layers (bf16 in, fp32 accum).
// ---------------------------------------------------------------------------
__global__ void dot_gemm(const unsigned short* __restrict__ A,
                         const unsigned short* __restrict__ Wt,
                         const float* __restrict__ bias,
                         float* __restrict__ Cf, unsigned short* __restrict__ Cb,
                         int M, int N, int K, int act)
{
  int wid = blockIdx.x * 4 + (threadIdx.x >> 6);
  if (wid >= M * N) return;
  int m = wid / N, n = wid - m * N;
  int lane = threadIdx.x & 63;
  float s = 0.f;
  for (int k = lane * 8; k < K; k += 512) {
    short8v a = *(const short8v*)(A + (long long)m * K + k);
    short8v w = *(const short8v*)(Wt + (long long)n * K + k);
    #pragma unroll
    for (int i = 0; i < 8; i++)
      s = fmaf(b2f((unsigned short)a[i]), b2f((unsigned short)w[i]), s);
  }
  s = wave_sum(s);
  if (lane == 0) {
    s += bias[n];
    if (act == 2) s = tanhf(s);
    if (Cf) Cf[(long long)m * N + n] = s;
    if (Cb) Cb[(long long)m * N + n] = f2b(s);
  }
}

// ---------------------------------------------------------------------------
// Row softmax (fp32 in). If Sb != null, writes ONLY bf16 result.
// ---------------------------------------------------------------------------
__global__ void softmax_rows(float* __restrict__ S, unsigned short* __restrict__ Sb,
                             int R, int L, int ld)
{
  int wid = blockIdx.x * (blockDim.x >> 6) + (threadIdx.x >> 6);
  if (wid >= R) return;
  int lane = threadIdx.x & 63;
  float* p = S + (long long)wid * ld;
  float v[8];
  float m = -1e30f;
  #pragma unroll
  for (int i = 0; i < 8; i++) {
    int idx = lane + i * 64;
    v[i] = (idx < L) ? p[idx] : -1e30f;
    m = fmaxf(m, v[i]);
  }
  m = wave_max(m);
  float s = 0.f;
  #pragma unroll
  for (int i = 0; i < 8; i++) {
    v[i] = expf(v[i] - m);
    if (lane + i * 64 < L) s += v[i];
  }
  s = wave_sum(s);
  float inv = 1.f / s;
  #pragma unroll
  for (int i = 0; i < 8; i++) {
    int idx = lane + i * 64;
    if (idx < L) {
      float r = v[i] * inv;
      if (Sb) Sb[(long long)wid * ld + idx] = f2b(r);
      else    p[idx] = r;
    }
  }
}

// ---------------------------------------------------------------------------
// Fused add + LayerNorm, D=512. fp32 out (+ optional bf16 out). accum: +=.
// ---------------------------------------------------------------------------
__global__ void ln_rows(const float* __restrict__ a, const float* __restrict__ b,
                        const float* __restrict__ c, const float* __restrict__ gb,
                        float* __restrict__ out, unsigned short* __restrict__ outb,
                        int rows, int accum)
{
  int wid = blockIdx.x * (blockDim.x >> 6) + (threadIdx.x >> 6);
  if (wid >= rows) return;
  int lane = threadIdx.x & 63;
  long long base = (long long)wid * DM;
  float x[8]; float s = 0.f;
  #pragma unroll
  for (int i = 0; i < 8; i++) {
    int d = lane + i * 64;
    float v = a[base + d];
    if (b) v += b[base + d];
    if (c) v += c[base + d];
    x[i] = v; s += v;
  }
  s = wave_sum(s);
  float mean = s * (1.f / DM);
  float vs = 0.f;
  #pragma unroll
  for (int i = 0; i < 8; i++) { float d = x[i] - mean; vs += d * d; }
  vs = wave_sum(vs);
  float rstd = rsqrtf(vs * (1.f / DM) + 1e-5f);
  #pragma unroll
  for (int i = 0; i < 8; i++) {
    int d = lane + i * 64;
    float val = (x[i] - mean) * rstd * gb[d] + gb[DM + d];
    if (accum) out[base + d] += val; else out[base + d] = val;
    if (outb) outb[base + d] = f2b(val);
  }
}

// ---------------------------------------------------------------------------
// Banded attention for one window: acc[8] = softmax(q.K^T) @ V for this
// wave's row. Per-j unrolled (no staging arrays); interior fast path.
// ---------------------------------------------------------------------------
template<int W>
__device__ __forceinline__ void banded_acc(const unsigned short* __restrict__ q,
                                           const unsigned short* __restrict__ k,
                                           const unsigned short* __restrict__ v,
                                           long long rowbase, int t, float* acc)
{
  constexpr int NJ = 2 * W + 1;
  const float SC128 = 0.08838834764831845f;
  const bool interior = (t >= W) && (t < 480 - W);

  float qv[8];
  { short8v x = *(const short8v*)(q + rowbase);
    #pragma unroll
    for (int i = 0; i < 8; i++) qv[i] = b2f((unsigned short)x[i]) * SC128; }

  const unsigned short* kbase = k + rowbase - (long long)W * 512;
  const unsigned short* vbase = v + rowbase - (long long)W * 512;

  float s[NJ];
  if (interior) {
    #pragma unroll
    for (int j = 0; j < NJ; j++) {
      short8v x = *(const short8v*)(kbase + (long long)j * 512);
      float d = 0.f;
      #pragma unroll
      for (int i = 0; i < 8; i++) d = fmaf(qv[i], b2f((unsigned short)x[i]), d);
      d += __shfl_xor(d, 1); d += __shfl_xor(d, 2);
      d += __shfl_xor(d, 4); d += __shfl_xor(d, 8);
      s[j] = d;
    }
  } else {
    #pragma unroll
    for (int j = 0; j < NJ; j++) {
      int tt = t + j - W;
      float d = -1e30f;
      if ((unsigned)tt < 480u) {
        short8v x = *(const short8v*)(kbase + (long long)j * 512);
        d = 0.f;
        #pragma unroll
        for (int i = 0; i < 8; i++) d = fmaf(qv[i], b2f((unsigned short)x[i]), d);
        d += __shfl_xor(d, 1); d += __shfl_xor(d, 2);
        d += __shfl_xor(d, 4); d += __shfl_xor(d, 8);
      }
      s[j] = d;
    }
  }

  float m = s[0];
  #pragma unroll
  for (int j = 1; j < NJ; j++) m = fmaxf(m, s[j]);
  float sum = 0.f;
  #pragma unroll
  for (int j = 0; j < NJ; j++) { s[j] = expf(s[j] - m); sum += s[j]; }
  float inv = 1.f / sum;

  if (interior) {
    #pragma unroll
    for (int j = 0; j < NJ; j++) {
      short8v x = *(const short8v*)(vbase + (long long)j * 512);
      float p = s[j] * inv;
      #pragma unroll
      for (int i = 0; i < 8; i++) acc[i] = fmaf(p, b2f((unsigned short)x[i]), acc[i]);
    }
  } else {
    #pragma unroll
    for (int j = 0; j < NJ; j++) {
      int tt = t + j - W;
      if ((unsigned)tt < 480u) {
        short8v x = *(const short8v*)(vbase + (long long)j * 512);
        float p = s[j] * inv;
        #pragma unroll
        for (int i = 0; i < 8; i++) acc[i] = fmaf(p, b2f((unsigned short)x[i]), acc[i]);
      }
    }
  }
}

// ---------------------------------------------------------------------------
// Pair-fused sliding-window attention + residual-LN, XCD-chunked swizzle.
// mode 0: MS = sum;  mode 2: outB = f2b((MS + sum) * 0.25)
// ---------------------------------------------------------------------------
template<int W1, int W2>
__global__ void slide_attn2_ln(const unsigned short* __restrict__ q1,
                               const unsigned short* __restrict__ k1,
                               const unsigned short* __restrict__ v1,
                               const unsigned short* __restrict__ q2,
                               const unsigned short* __restrict__ k2,
                               const unsigned short* __restrict__ v2,
                               const float* __restrict__ Afp,
                               const float* __restrict__ gb1,
                               const float* __restrict__ gb2,
                               float* __restrict__ MS,
                               unsigned short* __restrict__ outB, int mode)
{
  // bijective chunked swizzle (nwg divisible by 8)
  int nwg = gridDim.x;
  int orig = blockIdx.x;
  int blk = (orig & 7) * (nwg >> 3) + (orig >> 3);
  int wid = blk * (blockDim.x >> 6) + (threadIdx.x >> 6);
  if (wid >= 32 * 480) return;
  int lane = threadIdx.x & 63;
  int t = wid % 480;
  long long rowbase = (long long)wid * 512 + lane * 8;

  float arow[8];
  #pragma unroll
  for (int i = 0; i < 8; i++) arow[i] = Afp[rowbase + i];

  float msum[8] = {};
  // ---- window 1 ----
  {
    float acc[8] = {};
    banded_acc<W1>(q1, k1, v1, rowbase, t, acc);
    float x[8]; float ss = 0.f;
    #pragma unroll
    for (int i = 0; i < 8; i++) { x[i] = arow[i] + acc[i]; ss += x[i]; }
    ss = wave_sum(ss);
    float mean = ss * (1.f / DM);
    float vs = 0.f;
    #pragma unroll
    for (int i = 0; i < 8; i++) { float d = x[i] - mean; vs += d * d; }
    vs = wave_sum(vs);
    float rstd = rsqrtf(vs * (1.f / DM) + 1e-5f);
    #pragma unroll
    for (int i = 0; i < 8; i++) {
      int d = lane * 8 + i;
      msum[i] += (x[i] - mean) * rstd * gb1[d] + gb1[DM + d];
    }
  }
  // ---- window 2 ----
  {
    float acc[8] = {};
    banded_acc<W2>(q2, k2, v2, rowbase, t, acc);
    float x[8]; float ss = 0.f;
    #pragma unroll
    for (int i = 0; i < 8; i++) { x[i] = arow[i] + acc[i]; ss += x[i]; }
    ss = wave_sum(ss);
    float mean = ss * (1.f / DM);
    float vs = 0.f;
    #pragma unroll
    for (int i = 0; i < 8; i++) { float d = x[i] - mean; vs += d * d; }
    vs = wave_sum(vs);
    float rstd = rsqrtf(vs * (1.f / DM) + 1e-5f);
    #pragma unroll
    for (int i = 0; i < 8; i++) {
      int d = lane * 8 + i;
      msum[i] += (x[i] - mean) * rstd * gb2[d] + gb2[DM + d];
    }
  }

  if (mode == 0) {
    #pragma unroll
    for (int i = 0; i < 8; i++) MS[rowbase + i] = msum[i];
  } else {
    #pragma unroll
    for (int i = 0; i < 8; i++)
      outB[rowbase + i] = f2b((MS[rowbase + i] + msum[i]) * 0.25f);
  }
}

// ---------------------------------------------------------------------------
// mean over time, two-phase. part[b][g][d] = sum_{t in g} fused[b][t][d]
__global__ void mean_part(const float* __restrict__ fused, float* __restrict__ part)
{
  int b = blockIdx.x, g = blockIdx.y, d = threadIdx.x;
  float s0 = 0.f, s1 = 0.f, s2 = 0.f;
  int t0 = g * 30;
  for (int t = t0; t < t0 + 30; t += 3) {
    s0 += fused[(long long)(b * 480 + t) * 512 + d];
    s1 += fused[(long long)(b * 480 + t + 1) * 512 + d];
    s2 += fused[(long long)(b * 480 + t + 2) * 512 + d];
  }
  part[(long long)(b * 16 + g) * 512 + d] = s0 + s1 + s2;
}
// comb_b[b][0:512] = mean fused; comb_b[b][512:1024] = mean qstf. bf16 out.
__global__ void mean_fin(const float* __restrict__ part, const float* __restrict__ qstf,
                         unsigned short* __restrict__ comb)
{
  int b = blockIdx.x, d = threadIdx.x;
  float s = 0.f;
  #pragma unroll
  for (int g = 0; g < 16; g++) s += part[(long long)(b * 16 + g) * 512 + d];
  comb[b * 1024 + d] = f2b(s * (1.f / 480.f));
  float s2 = 0.f;
  for (int l = 0; l < 20; l += 2) {
    s2 += qstf[(long long)(b * 20 + l) * 512 + d];
    s2 += qstf[(long long)(b * 20 + l + 1) * 512 + d];
  }
  comb[b * 1024 + 512 + d] = f2b(s2 * (1.f / 20.f));
}

// fp32 [M][K] -> bf16 [M][Kp] (zero pad), with scale
__global__ void conv_act(const float* __restrict__ X, unsigned short* __restrict__ Xb,
                         int M, int K, int Kp, float sc)
{
  long long idx = (long long)blockIdx.x * 256 + threadIdx.x;
  if (idx >= (long long)M * Kp) return;
  int m = idx / Kp, k2 = idx - (long long)m * Kp;
  float v = (k2 < K) ? X[(long long)m * K + k2] * sc : 0.f;
  Xb[idx] = f2b(v);
}

// ---------------------------------------------------------------------------
// Batched weight transpose+convert: one launch handles many matrices.
// ---------------------------------------------------------------------------
struct TcD { const float* src; unsigned short* dst; int K, Kp, N, ldw; };
struct TcTab { TcD d[18]; int n; };

__global__ void transconv_all(TcTab tab)
{
  if ((int)blockIdx.z >= tab.n) return;
  TcD tc = tab.d[blockIdx.z];
  int k0 = blockIdx.x * 32, n0 = blockIdx.y * 32;
  if (k0 >= tc.Kp || n0 >= tc.N) return;
  __shared__ float T[32][33];
  int tx = threadIdx.x & 31, ty = threadIdx.x >> 5;
  #pragma unroll
  for (int r = 0; r < 4; r++) {
    int kk = k0 + ty + r * 8, n = n0 + tx;
    T[ty + r * 8][tx] = (kk < tc.K && n < tc.N) ? tc.src[(long long)kk * tc.ldw + n] : 0.f;
  }
  __syncthreads();
  #pragma unroll
  for (int r = 0; r < 4; r++) {
    int n = n0 + ty + r * 8, kk = k0 + tx;
    if (n < tc.N && kk < tc.Kp) tc.dst[(long long)n * tc.Kp + kk] = f2b(T[tx][ty + r * 8]);
  }
}

// ---------------------------------------------------------------------------

extern "C" void kernel_launch(void* const* d_in, const int* in_sizes, int n_in,
                              void* d_out, int out_size, void* d_ws, size_t ws_size,
                              hipStream_t stream)
{
  int ii = 0;
  const float* audio      = (const float*)d_in[ii++]; // 0
  const float* question   = (const float*)d_in[ii++];
  const float* audio_fc_w = (const float*)d_in[ii++];
  const float* audio_fc_b = (const float*)d_in[ii++];
  const float* qst_fc_w   = (const float*)d_in[ii++];
  const float* qst_fc_b   = (const float*)d_in[ii++]; // 5
  const float* attnq_in_w = (const float*)d_in[ii++];
  const float* attnq_in_b = (const float*)d_in[ii++];
  const float* attnq_out_w= (const float*)d_in[ii++];
  const float* attnq_out_b= (const float*)d_in[ii++];
  const float* qq_lin1_w  = (const float*)d_in[ii++]; // 10
  const float* qq_lin1_b  = (const float*)d_in[ii++];
  const float* qq_lin2_w  = (const float*)d_in[ii++];
  const float* qq_lin2_b  = (const float*)d_in[ii++];
  const float* qq_ln      = (const float*)d_in[ii++];
  const float* sa_in_w    = (const float*)d_in[ii++]; // 15
  const float* sa_in_b    = (const float*)d_in[ii++];
  const float* sa_out_w   = (const float*)d_in[ii++];
  const float* sa_out_b   = (const float*)d_in[ii++];
  const float* cm_in_w    = (const float*)d_in[ii++];
  const float* cm_in_b    = (const float*)d_in[ii++]; // 20
  const float* cm_out_w   = (const float*)d_in[ii++];
  const float* cm_out_b   = (const float*)d_in[ii++];
  const float* ff1_w      = (const float*)d_in[ii++];
  const float* ff1_b      = (const float*)d_in[ii++];
  const float* ff2_w      = (const float*)d_in[ii++]; // 25
  const float* ff2_b      = (const float*)d_in[ii++];
  const float* ln1        = (const float*)d_in[ii++];
  const float* ln2        = (const float*)d_in[ii++];
  const float* ms_qkv_w   = (const float*)d_in[ii++];
  const float* ms_qkv_b   = (const float*)d_in[ii++]; // 30
  const float* ms_ln      = (const float*)d_in[ii++];
  const float* msl_w      = (const float*)d_in[ii++];
  const float* msl_b      = (const float*)d_in[ii++];
  const float* ms_norm    = (const float*)d_in[ii++];
  const float* qa_in_w    = (const float*)d_in[ii++]; // 35
  const float* qa_in_b    = (const float*)d_in[ii++];
  const float* qa_out_w   = (const float*)d_in[ii++];
  const float* qa_out_b   = (const float*)d_in[ii++];
  const float* qa_ff1_w   = (const float*)d_in[ii++];
  const float* qa_ff1_b   = (const float*)d_in[ii++]; // 40
  const float* qa_ff2_w   = (const float*)d_in[ii++];
  const float* qa_ff2_b   = (const float*)d_in[ii++];
  const float* qa_ln1     = (const float*)d_in[ii++];
  const float* qa_ln2     = (const float*)d_in[ii++];
  const float* fc1_w      = (const float*)d_in[ii++]; // 45
  const float* fc1_b      = (const float*)d_in[ii++];
  const float* fc2_w      = (const float*)d_in[ii++];
  const float* fc2_b      = (const float*)d_in[ii++];
  const float* pred_w     = (const float*)d_in[ii++];
  const float* pred_b     = (const float*)d_in[ii++]; // 50
  (void)in_sizes; (void)n_in; (void)out_size; (void)ws_size;

  // ---- arena (~226.7 MB; bf16 B1..B3 immediately followed by P0,P1 so the
  //      six stage-5 QKV segments are one contiguous stride-NB run) ----
  char* base = (char*)d_ws;
  size_t off = 0;
  auto alloc_f = [&](size_t n) {
    float* p = (float*)(base + off);
    off += ((n * 4 + 255) & ~(size_t)255);
    return p;
  };
  auto alloc_h = [&](size_t n) {
    unsigned short* p = (unsigned short*)(base + off);
    off += ((n * 2 + 255) & ~(size_t)255);
    return p;
  };
  const size_t NB = (size_t)15360 * 512;
  // fp32 NB buffers
  float* A  = alloc_f(NB);
  float* MS = alloc_f(NB);
  // bf16 NB buffers (contiguous run: B1,B2,B3, then P0/P1 fp32 right after)
  unsigned short* Ab = alloc_h(NB);
  unsigned short* B1 = alloc_h(NB);
  unsigned short* B2 = alloc_h(NB);
  unsigned short* B3 = alloc_h(NB);
  float* P0 = alloc_f(NB);
  float* P1 = alloc_f(NB);
  // small fp32
  float* SBq = alloc_f((size_t)61440 * 20);   // narrow (L=20) scores; later: mean partials
  float* QF = alloc_f((size_t)640 * 512);
  float* q0 = alloc_f((size_t)640 * 512);     // q0,q1,q2 contiguous
  float* q1 = alloc_f((size_t)640 * 512);
  float* q2 = alloc_f((size_t)640 * 512);
  float* t1 = alloc_f((size_t)640 * 512);
  // small bf16
  unsigned short* COMBb = alloc_h((size_t)32 * 1024);
  unsigned short* C1b   = alloc_h((size_t)32 * 512);
  unsigned short* C2b   = alloc_h((size_t)32 * 256);
  unsigned short* QGb = alloc_h((size_t)640 * 512);
  unsigned short* QFb = alloc_h((size_t)640 * 512);
  unsigned short* audio_b = alloc_h((size_t)15360 * 128);
  unsigned short* quest_b = alloc_h((size_t)640 * 320);
  unsigned short* wb = alloc_h((size_t)10272000);
  (void)alloc_h(131072); // 256KB tail slack for staging overreads

  // aliases (lifetime-checked):
  float* SB = P1;                             // dense scores (32 x 480 x 480 f32)
  unsigned short* SBb3 = (unsigned short*)MS; // stage-3 bf16 probs (MS born in stage 5)
  unsigned short* SBb7 = (unsigned short*)A;  // stage-7 bf16 probs (A dead after stage 6 proj)
  float* PART = SBq;                          // stage-8 mean partials (SBq dead after stage 6)
  unsigned short* QB2 = (unsigned short*)P0;  // stage-5 window-B QKV (== B3 + NB)

  const float SC128 = 0.08838834764831845f;
  const float SC512 = 0.04419417382415922f;

  auto mf = [&](const unsigned short* Am, const unsigned short* Btm, const float* bias,
                float* Cm, unsigned short* Cbm, int M, int N, int K,
                int lda, int ldb, int ldc, long long aB, long long bB, long long cB,
                int Z, float preS, float postS, int act, int omode) {
    if (N <= 512) {
      dim3 g((N + 63) / 64, (M + 127) / 128, Z);
      gemm_mfma<2><<<g, 256, 0, stream>>>(Am, Btm, bias, Cm, Cbm, M, N, K, lda, ldb, ldc,
                                          aB, bB, cB, preS, postS, act, omode);
    } else {
      dim3 g((N + 127) / 128, (M + 127) / 128, Z);
      gemm_mfma<4><<<g, 256, 0, stream>>>(Am, Btm, bias, Cm, Cbm, M, N, K, lda, ldb, ldc,
                                          aB, bB, cB, preS, postS, act, omode);
    }
  };
  auto gemm = [&](const float* Am, const float* Bm, const float* bias, float* Cm,
                  unsigned short* Cbm,
                  int M, int N, int K, int lda, int ldb, int ldc,
                  long long aB, long long aH, long long bB, long long bH,
                  long long cB, long long cH, int Z, int nh, bool tB,
                  float preS, float postS, int act) {
    dim3 g((N + 63) / 64, (M + 63) / 64, Z);
    gemm_f32<<<g, 256, 0, stream>>>(Am, Bm, bias, Cm, Cbm, M, N, K, lda, ldb, ldc,
                                    aB, aH, bB, bH, cB, cH, nh, tB ? 1 : 0, preS, postS, act);
  };
  auto softmax = [&](float* S, unsigned short* Sb, int R, int L, int ld) {
    softmax_rows<<<dim3((R + 3) / 4), 256, 0, stream>>>(S, Sb, R, L, ld);
  };
  auto ln = [&](const float* a, const float* b, const float* c, const float* gb,
                float* outp, unsigned short* outbp, int rows, int accum) {
    ln_rows<<<dim3((rows + 3) / 4), 256, 0, stream>>>(a, b, c, gb, outp, outbp, rows, accum);
  };
  auto dot = [&](const unsigned short* Am, const unsigned short* Wtm, const float* bias,
                 float* Cf, unsigned short* Cb, int M, int N, int K, int act) {
    dot_gemm<<<dim3((M * N + 3) / 4), 256, 0, stream>>>(Am, Wtm, bias, Cf, Cb, M, N, K, act);
  };

  // ---- weight buffer layout ----
  unsigned short* wp = wb;
  auto WT = [&](size_t n) { unsigned short* r = wp; wp += n; return r; };
  unsigned short* wt_audio   = WT(512 * 128);
  unsigned short* wt_qst     = WT(512 * 320);
  unsigned short* wt_aq_in   = WT(3 * 262144);
  unsigned short* wt_aq_out  = WT(262144);
  unsigned short* wt_qq1     = WT(262144);
  unsigned short* wt_qq2     = WT(262144);
  unsigned short* wt_cm_in   = WT(3 * 262144);
  unsigned short* wt_cm_out  = WT(262144);
  unsigned short* wt_sa_in   = WT(3 * 262144);
  unsigned short* wt_sa_out  = WT(262144);
  unsigned short* wt_ff1     = WT(262144);
  unsigned short* wt_ff2     = WT(262144);
  unsigned short* wt_ms      = WT(12 * 262144);
  unsigned short* wt_msl     = WT(262144);
  unsigned short* wt_qa_in   = WT(3 * 262144);
  unsigned short* wt_qa_out  = WT(262144);
  unsigned short* wt_qa_ff1  = WT(262144);
  unsigned short* wt_qa_ff2  = WT(262144);
  unsigned short* wt_fc1     = WT(512 * 1024);
  unsigned short* wt_fc2     = WT(256 * 512);
  unsigned short* wt_pred    = WT(828 * 256);

  // ---- batched weight conversion: 3 launches ----
  {
    TcTab tA1 = {}; int n = 0;
    for (int z = 0; z < 3; z++)
      tA1.d[n++] = {attnq_in_w + z * 512, wt_aq_in + (size_t)z * 262144, 512, 512, 512, 1536};
    tA1.d[n++] = {attnq_out_w, wt_aq_out, 512, 512, 512, 512};
    tA1.d[n++] = {qq_lin1_w, wt_qq1, 512, 512, 512, 512};
    tA1.d[n++] = {qq_lin2_w, wt_qq2, 512, 512, 512, 512};
    for (int z = 0; z < 3; z++)
      tA1.d[n++] = {cm_in_w + z * 512, wt_cm_in + (size_t)z * 262144, 512, 512, 512, 1536};
    tA1.d[n++] = {cm_out_w, wt_cm_out, 512, 512, 512, 512};
    for (int z = 0; z < 3; z++)
      tA1.d[n++] = {sa_in_w + z * 512, wt_sa_in + (size_t)z * 262144, 512, 512, 512, 1536};
    tA1.d[n++] = {sa_out_w, wt_sa_out, 512, 512, 512, 512};
    tA1.d[n++] = {ff1_w, wt_ff1, 512, 512, 512, 512};
    tA1.d[n++] = {ff2_w, wt_ff2, 512, 512, 512, 512};
    for (int m = 0; m < 2; m++)
      tA1.d[n++] = {ms_qkv_w + (size_t)m * 262144, wt_ms + (size_t)m * 262144, 512, 512, 512, 512};
    tA1.n = n;  // 18
    transconv_all<<<dim3(16, 16, 18), 256, 0, stream>>>(tA1);

    TcTab tA2 = {}; n = 0;
    for (int m = 2; m < 12; m++)
      tA2.d[n++] = {ms_qkv_w + (size_t)m * 262144, wt_ms + (size_t)m * 262144, 512, 512, 512, 512};
    tA2.d[n++] = {msl_w, wt_msl, 512, 512, 512, 512};
    for (int z = 0; z < 3; z++)
      tA2.d[n++] = {qa_in_w + (size_t)3 * 512 * 1536 + z * 512, wt_qa_in + (size_t)z * 262144, 512, 512, 512, 1536};
    tA2.d[n++] = {qa_out_w + (size_t)3 * 262144, wt_qa_out, 512, 512, 512, 512};
    tA2.d[n++] = {qa_ff1_w + (size_t)3 * 262144, wt_qa_ff1, 512, 512, 512, 512};
    tA2.d[n++] = {qa_ff2_w + (size_t)3 * 262144, wt_qa_ff2, 512, 512, 512, 512};
    tA2.n = n;  // 17
    transconv_all<<<dim3(16, 16, 17), 256, 0, stream>>>(tA2);

    TcTab tB = {}; int n2 = 0;
    tB.d[n2++] = {audio_fc_w, wt_audio, 128, 128, 512, 512};
    tB.d[n2++] = {qst_fc_w, wt_qst, 300, 320, 512, 512};
    tB.d[n2++] = {fc1_w, wt_fc1, 1024, 1024, 512, 512};
    tB.d[n2++] = {fc2_w, wt_fc2, 512, 512, 256, 256};
    tB.d[n2++] = {pred_w, wt_pred, 256, 256, 828, 828};
    tB.n = n2;  // 5
    transconv_all<<<dim3(32, 26, 5), 256, 0, stream>>>(tB);
  }

  // ---- activation input conversion ----
  conv_act<<<dim3((15360 * 128 + 255) / 256), 256, 0, stream>>>(audio, audio_b, 15360, 128, 128, 1.f);
  conv_act<<<dim3((640 * 320 + 255) / 256), 256, 0, stream>>>(question, quest_b, 640, 300, 320, 1.f);

  // ---- stage 0: input projections ----
  mf(audio_b, wt_audio, audio_fc_b, A, Ab, 15360, 512, 128, 128, 128, 512, 0, 0, 0, 1, 1.f, 1.f, 0, 3);
  mf(quest_b, wt_qst, qst_fc_b, nullptr, QGb, 640, 512, 320, 320, 320, 512, 0, 0, 0, 1, 1.f, 1.f, 0, 2);

  // ---- stage 1: question self-attn (h=4, fused QKV) + qst_query_block -> QF ----
  mf(QGb, wt_aq_in, attnq_in_b, q0, nullptr, 640, 1536, 512, 512, 512, 512,
     0, 0, (long long)640 * 512, 1, 1.f, 1.f, 0, 1 | 16);
  gemm(q0, q1, nullptr, SBq, nullptr, 20, 20, 128, 512, 512, 20,
       20 * 512, 128, 20 * 512, 128, 1600, 400, 128, 4, true, SC128, 1.f, 0);
  softmax(SBq, nullptr, 2560, 20, 20);
  gemm(SBq, q2, nullptr, nullptr, B1, 20, 128, 20, 20, 512, 512,
       1600, 400, 20 * 512, 128, 20 * 512, 128, 128, 4, false, 1.f, 1.f, 0);
  mf(B1, wt_aq_out, attnq_out_b, t1, B2, 640, 512, 512, 512, 512, 512, 0, 0, 0, 1, 1.f, 1.f, 0, 3);
  mf(B2, wt_qq1, qq_lin1_b, nullptr, B1, 640, 512, 512, 512, 512, 512, 0, 0, 0, 1, 1.f, 1.f, 1, 2);
  mf(B1, wt_qq2, qq_lin2_b, q0, nullptr, 640, 512, 512, 512, 512, 512, 0, 0, 0, 1, 1.f, 1.f, 0, 1);
  ln(t1, q0, nullptr, qq_ln, QF, QFb, 640, 0);

  // ---- stage 2: s1 = cross-attn(A, QG, QG) h=1 -> P0 ----
  mf(Ab,  wt_cm_in,              cm_in_b + 0,    nullptr, B1, 15360, 512, 512, 512, 512, 512, 0, 0, 0, 1, 1.f, 1.f, 0, 2);
  mf(QGb, wt_cm_in + 262144,     cm_in_b + 512,  nullptr, B3, 640, 512, 512, 512, 512, 512, 0, 0, 0, 1, 1.f, 1.f, 0, 2);
  mf(QGb, wt_cm_in + 2 * 262144, cm_in_b + 1024, q2, nullptr, 640, 512, 512, 512, 512, 512, 0, 0, 0, 1, 1.f, 1.f, 0, 1);
  mf(B1, B3, nullptr, SBq, nullptr, 480, 20, 512, 512, 512, 20,
     480 * 512, 20 * 512, 9600, 32, SC512, 1.f, 0, 1);
  softmax(SBq, nullptr, 15360, 20, 20);
  gemm(SBq, q2, nullptr, nullptr, B1, 480, 512, 20, 20, 512, 512,
       9600, 0, 20 * 512, 0, 480 * 512, 0, 32, 1, false, 1.f, 1.f, 0);
  mf(B1, wt_cm_out, cm_out_b, P0, nullptr, 15360, 512, 512, 512, 512, 512, 0, 0, 0, 1, 1.f, 1.f, 0, 1);

  // ---- stage 3: s2 = dense self-attn(A) h=1, accumulate into P0 ----
  mf(Ab, wt_sa_in, sa_in_b, nullptr, B1, 15360, 1024, 512, 512, 512, 512,
     0, 0, (long long)NB, 1, 1.f, 1.f, 0, 2 | 16);   // Q->B1, K->B2
  mf(Ab, wt_sa_in + 2 * 262144, sa_in_b + 1024, nullptr, B3, 15360, 512, 512, 512, 512, 512, 0, 0, 0, 1, 1.f, 1.f, 0, 4);
  mf(B1, B2, nullptr, SB, nullptr, 480, 480, 512, 512, 512, 480,
     480 * 512, 480 * 512, 480 * 480, 32, SC512, 1.f, 0, 1);
  softmax(SB, SBb3, 15360, 480, 480);
  mf(SBb3, B3, nullptr, nullptr, B1, 480, 512, 480, 480, 480, 512,
     480 * 480, 512 * 480, 480 * 512, 32, 1.f, 1.f, 0, 2);
  mf(B1, wt_sa_out, sa_out_b, P0, nullptr, 15360, 512, 512, 512, 512, 512, 0, 0, 0, 1, 1.f, 1.f, 0, 9);  // P0 += s2

  // ---- stage 4: x = LN(A + s1+s2); audio_feat = LN(x + FFN(x)) -> A ----
  ln(A, P0, nullptr, ln1, P1, B1, 15360, 0);
  mf(B1, wt_ff1, ff1_b, nullptr, B2, 15360, 512, 512, 512, 512, 512, 0, 0, 0, 1, 1.f, 1.f, 1, 2);
  mf(B2, wt_ff2, ff2_b, P0, nullptr, 15360, 512, 512, 512, 512, 512, 0, 0, 0, 1, 1.f, 1.f, 0, 1);
  ln(P1, P0, nullptr, ln2, A, Ab, 15360, 0);

  // ---- stage 5: multi-window sliding attention (pair-fused, merged QKV) ----
  // pair p: ONE N=3072 projection -> 6 contiguous NB segments B1,B2,B3,QB2,+NB,+2NB
  for (int p = 0; p < 2; p++) {
    mf(Ab, wt_ms + (size_t)(p * 6) * 262144, ms_qkv_b + (size_t)(p * 6) * 512,
       nullptr, B1, 15360, 3072, 512, 512, 512, 512,
       0, 0, (long long)NB, 1, 1.f, 1.f, 0, 2 | 16);
    dim3 sg((32 * 480) / 4);
    if (p == 0)
      slide_attn2_ln<2, 4><<<sg, 256, 0, stream>>>(
          B1, B2, B3, QB2, QB2 + NB, QB2 + 2 * NB, A,
          ms_ln + 0, ms_ln + 1024, MS, nullptr, 0);
    else
      slide_attn2_ln<6, 12><<<sg, 256, 0, stream>>>(
          B1, B2, B3, QB2, QB2 + NB, QB2 + 2 * NB, A,
          ms_ln + 2048, ms_ln + 3072, MS, Ab, 2);
  }
  // Ab = bf16(0.25 * (ln0+ln1+ln2+ln3))  (multi-scale avg)
  mf(Ab, wt_msl, msl_b, P0, nullptr, 15360, 512, 512, 512, 512, 512, 0, 0, 0, 1, 1.f, 1.f, 0, 1);
  ln(A, P0, nullptr, ms_norm, A, Ab, 15360, 0);   // audio_feat

  // ---- stage 6: question-queried attn (h=4) + qq block -> av (MS f32, Ab bf16) ----
  mf(Ab,  wt_aq_in, attnq_in_b, P0, nullptr, 15360, 512, 512, 512, 512, 512, 0, 0, 0, 1, 1.f, 1.f, 0, 1);
  mf(QFb, wt_aq_in + 262144, attnq_in_b + 512, q1, nullptr, 640, 1024, 512, 512, 512, 512,
     0, 0, (long long)640 * 512, 1, 1.f, 1.f, 0, 1 | 16);  // K->q1, V->q2
  gemm(P0, q1, nullptr, SBq, nullptr, 480, 20, 128, 512, 512, 20,
       480 * 512, 128, 20 * 512, 128, 38400, 9600, 128, 4, true, SC128, 1.f, 0);
  softmax(SBq, nullptr, 61440, 20, 20);
  gemm(SBq, q2, nullptr, nullptr, B1, 480, 128, 20, 20, 512, 512,
       38400, 9600, 20 * 512, 128, 480 * 512, 128, 128, 4, false, 1.f, 1.f, 0);
  mf(B1, wt_aq_out, attnq_out_b, P0, B2, 15360, 512, 512, 512, 512, 512, 0, 0, 0, 1, 1.f, 1.f, 0, 3);
  mf(B2, wt_qq1, qq_lin1_b, nullptr, B3, 15360, 512, 512, 512, 512, 512, 0, 0, 0, 1, 1.f, 1.f, 1, 2);
  mf(B3, wt_qq2, qq_lin2_b, P1, nullptr, 15360, 512, 512, 512, 512, 512, 0, 0, 0, 1, 1.f, 1.f, 0, 1);
  ln(P0, P1, nullptr, qq_ln, MS, Ab, 15360, 0);   // av

  // ---- stage 7: Encoder_QA layer 3 (h=1), dense MFMA attention on av ----
  const float* qa_inb3 = qa_in_b + (size_t)3 * 1536;
  mf(Ab, wt_qa_in, qa_inb3, nullptr, B1, 15360, 1024, 512, 512, 512, 512,
     0, 0, (long long)NB, 1, 1.f, 1.f, 0, 2 | 16);   // Q->B1, K->B2
  mf(Ab, wt_qa_in + 2 * 262144, qa_inb3 + 1024, nullptr, B3, 15360, 512, 512, 512, 512, 512, 0, 0, 0, 1, 1.f, 1.f, 0, 4);
  mf(B1, B2, nullptr, SB, nullptr, 480, 480, 512, 512, 512, 480,
     480 * 512, 480 * 512, 480 * 480, 32, SC512, 1.f, 0, 1);
  softmax(SB, SBb7, 15360, 480, 480);
  mf(SBb7, B3, nullptr, nullptr, B1, 480, 512, 480, 480, 480, 512,
     480 * 480, 512 * 480, 480 * 512, 32, 1.f, 1.f, 0, 2);
  mf(B1, wt_qa_out, qa_out_b + 3 * 512, P0, nullptr, 15360, 512, 512, 512, 512, 512, 0, 0, 0, 1, 1.f, 1.f, 0, 1);
  ln(MS, P0, nullptr, qa_ln1 + 3 * 1024, P1, B1, 15360, 0);
  mf(B1, wt_qa_ff1, qa_ff1_b + 3 * 512, nullptr, B2, 15360, 512, 512, 512, 512, 512, 0, 0, 0, 1, 1.f, 1.f, 1, 2);
  mf(B2, wt_qa_ff2, qa_ff2_b + 3 * 512, P0, nullptr, 15360, 512, 512, 512, 512, 512, 0, 0, 0, 1, 1.f, 1.f, 0, 1);
  ln(P1, P0, nullptr, qa_ln2 + 3 * 1024, MS, nullptr, 15360, 0);  // fused -> MS

  // ---- stage 8: head (wave-dot, bf16) ----
  mean_part<<<dim3(32, 16), 512, 0, stream>>>(MS, PART);
  mean_fin<<<32, 512, 0, stream>>>(PART, QF, COMBb);
  dot(COMBb, wt_fc1, fc1_b, nullptr, C1b, 32, 512, 1024, 2);
  dot(C1b, wt_fc2, fc2_b, nullptr, C2b, 32, 256, 512, 2);
  dot(C2b, wt_pred, pred_b, (float*)d_out, nullptr, 32, 828, 256, 0);
}